// Round 1
// baseline (2036.671 us; speedup 1.0000x reference)
//
#include <hip/hip_runtime.h>
#include <math.h>

#define Bz   32
#define Sz   2048
#define Hz   768
#define FMAXz 32
#define MSz  64
#define NHz  12
#define DHz  64
#define Lz   96
#define FFNz 3072
#define NTOK (Bz*Sz)

#define BM 128
#define BN 128
#define BK 16

// ---------- K0: segment ids / sep positions ----------
__global__ __launch_bounds__(256) void k_seg(
    const int* __restrict__ ids, const int* __restrict__ sep_p,
    int* __restrict__ segid, int* __restrict__ seppos,
    int* __restrict__ nsent, int* __restrict__ neff)
{
  int b = blockIdx.x, tid = threadIdx.x;
  int sep = *sep_p;
  __shared__ int cnt[256];
  __shared__ int total_s;
  const int* row = &ids[b*Sz];
  int base = tid*8;
  int loc[8];
  int c = 0;
  #pragma unroll
  for (int i = 0; i < 8; i++) { loc[i] = row[base+i]; c += (loc[i]==sep) ? 1 : 0; }
  cnt[tid] = c;
  __syncthreads();
  if (tid == 0) {
    int run = 0;
    for (int t = 0; t < 256; t++) { int tmp = cnt[t]; cnt[t] = run; run += tmp; }
    total_s = run;
    nsent[b] = run;
    neff[b]  = run > 0 ? run : 1;
  }
  __syncthreads();
  int total = total_s;
  int seg = cnt[tid];
  #pragma unroll
  for (int i = 0; i < 8; i++) {
    int s = base + i;
    bool issep = (loc[i]==sep);
    if (issep && seg < MSz) seppos[b*MSz + seg] = s;
    bool valid = (s >= 1) && !issep && (seg < total);
    segid[b*Sz + s] = valid ? seg : -1;
    if (issep) seg++;
  }
}

// ---------- K1: fused scores GEMM: tanh(h1@Wp+bp)@vp ----------
__global__ __launch_bounds__(256) void k_scores(
    const float* __restrict__ h1, const float* __restrict__ Wp,
    const float* __restrict__ bp, const float* __restrict__ vp,
    float* __restrict__ scores)
{
  __shared__ float As[BK][132];
  __shared__ float Bs[BK][132];
  __shared__ float red[BM][17];
  const int tokBase = blockIdx.x * BM;
  const int tid = threadIdx.x;
  const int tx = tid & 15, ty = tid >> 4;
  float part[8] = {0,0,0,0,0,0,0,0};
  for (int j0 = 0; j0 < Hz; j0 += BN) {
    float acc[8][8];
    #pragma unroll
    for (int r = 0; r < 8; r++)
      #pragma unroll
      for (int cc = 0; cc < 8; cc++) acc[r][cc] = 0.f;
    for (int k0 = 0; k0 < Hz; k0 += BK) {
      #pragma unroll
      for (int l = 0; l < 8; l++) {
        int i = tid + l*256;
        int t = i >> 4, kk = i & 15;
        As[kk][t] = h1[(size_t)(tokBase + t)*Hz + k0 + kk];
      }
      #pragma unroll
      for (int l = 0; l < 8; l++) {
        int i = tid + l*256;
        int kk = i >> 7, jj = i & 127;
        Bs[kk][jj] = Wp[(size_t)(k0 + kk)*Hz + j0 + jj];
      }
      __syncthreads();
      #pragma unroll
      for (int kk = 0; kk < BK; kk++) {
        float4 a0 = *(const float4*)&As[kk][ty*4];
        float4 a1 = *(const float4*)&As[kk][64 + ty*4];
        float4 b0 = *(const float4*)&Bs[kk][tx*4];
        float4 b1 = *(const float4*)&Bs[kk][64 + tx*4];
        float a[8] = {a0.x,a0.y,a0.z,a0.w,a1.x,a1.y,a1.z,a1.w};
        float b[8] = {b0.x,b0.y,b0.z,b0.w,b1.x,b1.y,b1.z,b1.w};
        #pragma unroll
        for (int r = 0; r < 8; r++)
          #pragma unroll
          for (int cc = 0; cc < 8; cc++)
            acc[r][cc] += a[r]*b[cc];
      }
      __syncthreads();
    }
    #pragma unroll
    for (int cc = 0; cc < 8; cc++) {
      int j = j0 + ((cc < 4) ? (tx*4 + cc) : (64 + tx*4 + (cc-4)));
      float bpj = bp[j], vpj = vp[j];
      #pragma unroll
      for (int r = 0; r < 8; r++)
        part[r] += tanhf(acc[r][cc] + bpj) * vpj;
    }
  }
  #pragma unroll
  for (int r = 0; r < 8; r++) {
    int rowi = (r < 4) ? (ty*4 + r) : (64 + ty*4 + (r-4));
    red[rowi][tx] = part[r];
  }
  __syncthreads();
  if (tid < BM) {
    float s = 0;
    #pragma unroll
    for (int i = 0; i < 16; i++) s += red[tid][i];
    scores[tokBase + tid] = s;
  }
}

// ---------- K2: per-(b,seg) softmax ----------
__device__ inline unsigned fenc(float f){ unsigned u = __float_as_uint(f); return (u & 0x80000000u) ? ~u : (u | 0x80000000u); }
__device__ inline float fdec(unsigned u){ return (u & 0x80000000u) ? __uint_as_float(u & 0x7fffffffu) : __uint_as_float(~u); }

__global__ __launch_bounds__(256) void k_softmax_seg(
    const float* __restrict__ scores, const int* __restrict__ segid,
    float* __restrict__ w)
{
  int b = blockIdx.x, tid = threadIdx.x;
  __shared__ unsigned menc[MSz];
  __shared__ float msh[MSz];
  __shared__ float zsh[MSz];
  if (tid < MSz) { menc[tid] = 0u; zsh[tid] = 0.f; }
  __syncthreads();
  for (int s = tid; s < Sz; s += 256) {
    int g = segid[b*Sz + s];
    if (g >= 0 && g < MSz) atomicMax(&menc[g], fenc(scores[b*Sz+s]));
  }
  __syncthreads();
  if (tid < MSz) msh[tid] = fdec(menc[tid]);
  __syncthreads();
  for (int s = tid; s < Sz; s += 256) {
    int g = segid[b*Sz + s];
    float e = 0.f;
    if (g >= 0 && g < MSz) { e = expf(scores[b*Sz+s] - msh[g]); atomicAdd(&zsh[g], e); }
    w[b*Sz + s] = e;
  }
  __syncthreads();
  if (tid < MSz) zsh[tid] = (zsh[tid] > 0.f) ? 1.0f/zsh[tid] : 1.0f;
  __syncthreads();
  for (int s = tid; s < Sz; s += 256) {
    int g = segid[b*Sz + s];
    if (g >= 0 && g < MSz) w[b*Sz + s] *= zsh[g];
  }
}

// ---------- K3: weighted sentence sums -> x rows ----------
__global__ __launch_bounds__(256) void k_sent(
    const float* __restrict__ h1, const float* __restrict__ w,
    const int* __restrict__ seppos, const int* __restrict__ nsent,
    const int* __restrict__ neff, float* __restrict__ x)
{
  int s = blockIdx.x, b = blockIdx.y, tid = threadIdx.x;
  int ne = neff[b], ns = nsent[b];
  if (s >= ne) return;
  float* xr = &x[((size_t)b*Lz + s)*Hz];
  if (ns == 0) { // only s==0 possible (ne==1)
    const float* hr = &h1[(size_t)b*Sz*Hz];
    xr[tid] = hr[tid]; xr[tid+256] = hr[tid+256]; xr[tid+512] = hr[tid+512];
    return;
  }
  int start = (s == 0) ? 1 : seppos[b*MSz + s - 1] + 1;
  int end = seppos[b*MSz + s];
  float a0=0.f, a1=0.f, a2=0.f;
  for (int t = start; t < end; t++) {
    float wv = w[b*Sz + t];
    const float* hr = &h1[((size_t)b*Sz + t)*Hz];
    a0 += wv*hr[tid]; a1 += wv*hr[tid+256]; a2 += wv*hr[tid+512];
  }
  xr[tid]=a0; xr[tid+256]=a1; xr[tid+512]=a2;
}

// ---------- K4: place fact_cls rows ----------
__global__ __launch_bounds__(256) void k_facts(
    const float* __restrict__ fc, const int* __restrict__ fcnt,
    const int* __restrict__ neff, float* __restrict__ x)
{
  int f = blockIdx.x, b = blockIdx.y, tid = threadIdx.x;
  if (f >= fcnt[b]) return;
  int pos = neff[b] + f;
  if (pos >= Lz) return;
  float* xr = &x[((size_t)b*Lz + pos)*Hz];
  const float* fr = &fc[((size_t)b*FMAXz + f)*Hz];
  xr[tid] = fr[tid]; xr[tid+256] = fr[tid+256]; xr[tid+512] = fr[tid+512];
}

// ---------- pack [Wk|Wv], [bk|bv] ----------
__global__ __launch_bounds__(256) void k_packw(
    const float* __restrict__ Wk, const float* __restrict__ Wv,
    const float* __restrict__ bk, const float* __restrict__ bv,
    float* __restrict__ wcat, float* __restrict__ bcat)
{
  int k = blockIdx.x, tid = threadIdx.x;
  #pragma unroll
  for (int c = 0; c < 6; c++) {
    int j = tid + c*256;
    wcat[(size_t)k*1536 + j] = (j < Hz) ? Wk[(size_t)k*Hz + j] : Wv[(size_t)k*Hz + j - Hz];
  }
  if (k == 0) {
    #pragma unroll
    for (int c = 0; c < 6; c++) {
      int j = tid + c*256;
      bcat[j] = (j < Hz) ? bk[j] : bv[j - Hz];
    }
  }
}

// ---------- K5: C[M,N] = A[M,768]@W[768,N] + bias ----------
__global__ __launch_bounds__(256) void k_gemm_bias(
    const float* __restrict__ A, const float* __restrict__ W,
    const float* __restrict__ bias, float* __restrict__ C, int N)
{
  __shared__ float As[BK][132];
  __shared__ float Bs[BK][132];
  const int mBase = blockIdx.y * BM;
  const int j0 = blockIdx.x * BN;
  const int tid = threadIdx.x;
  const int tx = tid & 15, ty = tid >> 4;
  float acc[8][8];
  #pragma unroll
  for (int r = 0; r < 8; r++)
    #pragma unroll
    for (int cc = 0; cc < 8; cc++) acc[r][cc] = 0.f;
  for (int k0 = 0; k0 < Hz; k0 += BK) {
    #pragma unroll
    for (int l = 0; l < 8; l++) {
      int i = tid + l*256;
      int t = i >> 4, kk = i & 15;
      As[kk][t] = A[(size_t)(mBase + t)*Hz + k0 + kk];
    }
    #pragma unroll
    for (int l = 0; l < 8; l++) {
      int i = tid + l*256;
      int kk = i >> 7, jj = i & 127;
      Bs[kk][jj] = W[(size_t)(k0 + kk)*N + j0 + jj];
    }
    __syncthreads();
    #pragma unroll
    for (int kk = 0; kk < BK; kk++) {
      float4 a0 = *(const float4*)&As[kk][ty*4];
      float4 a1 = *(const float4*)&As[kk][64 + ty*4];
      float4 b0 = *(const float4*)&Bs[kk][tx*4];
      float4 b1 = *(const float4*)&Bs[kk][64 + tx*4];
      float a[8] = {a0.x,a0.y,a0.z,a0.w,a1.x,a1.y,a1.z,a1.w};
      float b[8] = {b0.x,b0.y,b0.z,b0.w,b1.x,b1.y,b1.z,b1.w};
      #pragma unroll
      for (int r = 0; r < 8; r++)
        #pragma unroll
        for (int cc = 0; cc < 8; cc++)
          acc[r][cc] += a[r]*b[cc];
    }
    __syncthreads();
  }
  float bb[8];
  #pragma unroll
  for (int cc = 0; cc < 8; cc++)
    bb[cc] = bias[j0 + ((cc < 4) ? (tx*4 + cc) : (64 + tx*4 + (cc-4)))];
  #pragma unroll
  for (int r = 0; r < 8; r++) {
    int rowi = (r < 4) ? (ty*4 + r) : (64 + ty*4 + (r-4));
    size_t base = (size_t)(mBase + rowi)*N;
    float4 v0 = {acc[r][0]+bb[0], acc[r][1]+bb[1], acc[r][2]+bb[2], acc[r][3]+bb[3]};
    float4 v1 = {acc[r][4]+bb[4], acc[r][5]+bb[5], acc[r][6]+bb[6], acc[r][7]+bb[7]};
    *(float4*)&C[base + j0 + tx*4] = v0;
    *(float4*)&C[base + j0 + 64 + tx*4] = v1;
  }
}

// ---------- K6: q row 0 only ----------
__global__ __launch_bounds__(256) void k_q0(
    const float* __restrict__ x, const float* __restrict__ Wq,
    const float* __restrict__ bq, float* __restrict__ q0)
{
  int b = blockIdx.x, tid = threadIdx.x;
  __shared__ float xs[Hz];
  for (int i = tid; i < Hz; i += 256) xs[i] = x[(size_t)b*Lz*Hz + i];
  __syncthreads();
  float a0 = bq[tid], a1 = bq[tid+256], a2 = bq[tid+512];
  for (int k = 0; k < Hz; k++) {
    float xv = xs[k];
    const float* wr = &Wq[(size_t)k*Hz];
    a0 += xv*wr[tid]; a1 += xv*wr[tid+256]; a2 += xv*wr[tid+512];
  }
  q0[b*Hz+tid] = a0; q0[b*Hz+tid+256] = a1; q0[b*Hz+tid+512] = a2;
}

// ---------- K7: attention for query row 0 ----------
__global__ __launch_bounds__(128) void k_attn(
    const float* __restrict__ q0, const float* __restrict__ kv,
    const int* __restrict__ neff, const int* __restrict__ fcnt,
    float* __restrict__ ctx0)
{
  int h = blockIdx.x, b = blockIdx.y, tid = threadIdx.x;
  __shared__ float att[Lz];
  __shared__ float qsh[DHz];
  __shared__ float inv_s;
  if (tid < DHz) qsh[tid] = q0[b*Hz + h*DHz + tid];
  __syncthreads();
  int lv = neff[b] + fcnt[b];
  if (tid < Lz) {
    const float* kr = &kv[((size_t)b*Lz + tid)*1536 + h*DHz];
    float s = 0.f;
    #pragma unroll
    for (int d = 0; d < DHz; d++) s += qsh[d]*kr[d];
    s *= 0.125f;
    if (tid >= lv) s -= 1e9f;
    att[tid] = s;
  }
  __syncthreads();
  if (tid == 0) {
    float m = att[0];
    for (int i = 1; i < Lz; i++) m = fmaxf(m, att[i]);
    float z = 0.f;
    for (int i = 0; i < Lz; i++) { float e = expf(att[i] - m); att[i] = e; z += e; }
    inv_s = 1.f/z;
  }
  __syncthreads();
  float inv = inv_s;
  if (tid < DHz) {
    float c = 0.f;
    for (int m2 = 0; m2 < Lz; m2++)
      c += att[m2] * kv[((size_t)b*Lz + m2)*1536 + Hz + h*DHz + tid];
    ctx0[b*Hz + h*DHz + tid] = c*inv;
  }
}

// ---------- block sum helper ----------
__device__ inline float block_sum_256(float v, float* red)
{
  int tid = threadIdx.x;
  red[tid] = v; __syncthreads();
  for (int off = 128; off > 0; off >>= 1) {
    if (tid < off) red[tid] += red[tid + off];
    __syncthreads();
  }
  float r = red[0];
  __syncthreads();
  return r;
}

// ---------- K8: row0 Wo projection + residual + LN1 ----------
__global__ __launch_bounds__(256) void k_attnout_ln1(
    const float* __restrict__ x, const float* __restrict__ ctx0,
    const float* __restrict__ Wo, const float* __restrict__ bo,
    const float* __restrict__ g, const float* __restrict__ bt,
    float* __restrict__ y0)
{
  int b = blockIdx.x, tid = threadIdx.x;
  __shared__ float cs[Hz];
  __shared__ float red[256];
  for (int i = tid; i < Hz; i += 256) cs[i] = ctx0[b*Hz + i];
  __syncthreads();
  float a0 = bo[tid], a1 = bo[tid+256], a2 = bo[tid+512];
  for (int i = 0; i < Hz; i++) {
    float cv = cs[i];
    const float* wr = &Wo[(size_t)i*Hz];
    a0 += cv*wr[tid]; a1 += cv*wr[tid+256]; a2 += cv*wr[tid+512];
  }
  const float* xr = &x[(size_t)b*Lz*Hz];
  a0 += xr[tid]; a1 += xr[tid+256]; a2 += xr[tid+512];
  float mu = block_sum_256(a0+a1+a2, red) * (1.0f/Hz);
  float d0=a0-mu, d1=a1-mu, d2=a2-mu;
  float var = block_sum_256(d0*d0+d1*d1+d2*d2, red) * (1.0f/Hz);
  float rs = rsqrtf(var + 1e-12f);
  y0[b*Hz+tid]     = d0*rs*g[tid]     + bt[tid];
  y0[b*Hz+tid+256] = d1*rs*g[tid+256] + bt[tid+256];
  y0[b*Hz+tid+512] = d2*rs*g[tid+512] + bt[tid+512];
}

// ---------- K9a: FFN up + exact gelu (row0 only) ----------
__global__ __launch_bounds__(256) void k_ffn1(
    const float* __restrict__ y0, const float* __restrict__ Wf1,
    const float* __restrict__ bf1, float* __restrict__ ffnmid)
{
  int b = blockIdx.x, tid = threadIdx.x;
  __shared__ float ys[Hz];
  for (int i = tid; i < Hz; i += 256) ys[i] = y0[b*Hz + i];
  __syncthreads();
  float a[12];
  #pragma unroll
  for (int c = 0; c < 12; c++) a[c] = bf1[tid + c*256];
  for (int j = 0; j < Hz; j++) {
    float yv = ys[j];
    const float* wr = &Wf1[(size_t)j*FFNz];
    #pragma unroll
    for (int c = 0; c < 12; c++) a[c] += yv * wr[tid + c*256];
  }
  #pragma unroll
  for (int c = 0; c < 12; c++) {
    float v = a[c];
    ffnmid[b*FFNz + tid + c*256] = 0.5f*v*(1.0f + erff(v*0.70710678118654752f));
  }
}

// ---------- K9b: FFN down + residual + LN2 -> out ----------
__global__ __launch_bounds__(256) void k_ffn2_ln2(
    const float* __restrict__ y0, const float* __restrict__ ffnmid,
    const float* __restrict__ Wf2, const float* __restrict__ bf2,
    const float* __restrict__ g, const float* __restrict__ bt,
    float* __restrict__ out)
{
  int b = blockIdx.x, tid = threadIdx.x;
  __shared__ float hs[FFNz];
  __shared__ float red[256];
  for (int i = tid; i < FFNz; i += 256) hs[i] = ffnmid[b*FFNz + i];
  __syncthreads();
  float a0 = bf2[tid], a1 = bf2[tid+256], a2 = bf2[tid+512];
  for (int f = 0; f < FFNz; f++) {
    float hv = hs[f];
    const float* wr = &Wf2[(size_t)f*Hz];
    a0 += hv*wr[tid]; a1 += hv*wr[tid+256]; a2 += hv*wr[tid+512];
  }
  a0 += y0[b*Hz+tid]; a1 += y0[b*Hz+tid+256]; a2 += y0[b*Hz+tid+512];
  float mu = block_sum_256(a0+a1+a2, red) * (1.0f/Hz);
  float d0=a0-mu, d1=a1-mu, d2=a2-mu;
  float var = block_sum_256(d0*d0+d1*d1+d2*d2, red) * (1.0f/Hz);
  float rs = rsqrtf(var + 1e-12f);
  out[b*Hz+tid]     = d0*rs*g[tid]     + bt[tid];
  out[b*Hz+tid+256] = d1*rs*g[tid+256] + bt[tid+256];
  out[b*Hz+tid+512] = d2*rs*g[tid+512] + bt[tid+512];
}

extern "C" void kernel_launch(void* const* d_in, const int* in_sizes, int n_in,
                              void* d_out, int out_size, void* d_ws, size_t ws_size,
                              hipStream_t stream)
{
  (void)in_sizes; (void)n_in; (void)out_size; (void)ws_size;
  const float* hidden1  = (const float*)d_in[0];
  const float* fact_cls = (const float*)d_in[1];
  const float* Wp   = (const float*)d_in[2];
  const float* bp   = (const float*)d_in[3];
  const float* vp   = (const float*)d_in[4];
  const float* Wq   = (const float*)d_in[5];
  const float* bq   = (const float*)d_in[6];
  const float* Wk   = (const float*)d_in[7];
  const float* bk   = (const float*)d_in[8];
  const float* Wv   = (const float*)d_in[9];
  const float* bv   = (const float*)d_in[10];
  const float* Wo   = (const float*)d_in[11];
  const float* bo   = (const float*)d_in[12];
  const float* ln1g = (const float*)d_in[13];
  const float* ln1b = (const float*)d_in[14];
  const float* Wf1  = (const float*)d_in[15];
  const float* bf1  = (const float*)d_in[16];
  const float* Wf2  = (const float*)d_in[17];
  const float* bf2  = (const float*)d_in[18];
  const float* ln2g = (const float*)d_in[19];
  const float* ln2b = (const float*)d_in[20];
  const int* input_ids   = (const int*)d_in[21];
  const int* facts_count = (const int*)d_in[22];
  const int* sep_id      = (const int*)d_in[24];

  char* ws = (char*)d_ws;
  size_t off = 0;
  auto alloc = [&](size_t bytes) -> void* {
    void* p = ws + off; off += (bytes + 255) & ~(size_t)255; return p;
  };
  float* x      = (float*)alloc(sizeof(float)*(size_t)Bz*Lz*Hz);
  float* kv     = (float*)alloc(sizeof(float)*(size_t)Bz*Lz*1536);
  float* wcat   = (float*)alloc(sizeof(float)*(size_t)Hz*1536);
  float* bcat   = (float*)alloc(sizeof(float)*1536);
  float* scores = (float*)alloc(sizeof(float)*NTOK);
  float* w      = (float*)alloc(sizeof(float)*NTOK);
  int*   segid  = (int*)alloc(sizeof(int)*NTOK);
  int*   seppos = (int*)alloc(sizeof(int)*Bz*MSz);
  int*   nsent  = (int*)alloc(sizeof(int)*Bz);
  int*   neff   = (int*)alloc(sizeof(int)*Bz);
  float* q0     = (float*)alloc(sizeof(float)*Bz*Hz);
  float* ctx0   = (float*)alloc(sizeof(float)*Bz*Hz);
  float* y0     = (float*)alloc(sizeof(float)*Bz*Hz);
  float* ffnmid = (float*)alloc(sizeof(float)*Bz*FFNz);

  hipMemsetAsync(x, 0, sizeof(float)*(size_t)Bz*Lz*Hz, stream);
  k_seg<<<Bz, 256, 0, stream>>>(input_ids, sep_id, segid, seppos, nsent, neff);
  k_scores<<<NTOK/BM, 256, 0, stream>>>(hidden1, Wp, bp, vp, scores);
  k_softmax_seg<<<Bz, 256, 0, stream>>>(scores, segid, w);
  k_sent<<<dim3(MSz, Bz), 256, 0, stream>>>(hidden1, w, seppos, nsent, neff, x);
  k_facts<<<dim3(FMAXz, Bz), 256, 0, stream>>>(fact_cls, facts_count, neff, x);
  k_packw<<<Hz, 256, 0, stream>>>(Wk, Wv, bk, bv, wcat, bcat);
  k_gemm_bias<<<dim3(1536/BN, (Bz*Lz)/BM), 256, 0, stream>>>(x, wcat, bcat, kv, 1536);
  k_q0<<<Bz, 256, 0, stream>>>(x, Wq, bq, q0);
  k_attn<<<dim3(NHz, Bz), 128, 0, stream>>>(q0, kv, neff, facts_count, ctx0);
  k_attnout_ln1<<<Bz, 256, 0, stream>>>(x, ctx0, Wo, bo, ln1g, ln1b, y0);
  k_ffn1<<<Bz, 256, 0, stream>>>(y0, Wf1, bf1, ffnmid);
  k_ffn2_ln2<<<Bz, 256, 0, stream>>>(y0, ffnmid, Wf2, bf2, ln2g, ln2b, (float*)d_out);
}

// Round 2
// 721.232 us; speedup vs baseline: 2.8239x; 2.8239x over previous
//
#include <hip/hip_runtime.h>
#include <math.h>

#define Bz   32
#define Sz   2048
#define Hz   768
#define FMAXz 32
#define MSz  64
#define NHz  12
#define DHz  64
#define Lz   96
#define FFNz 3072
#define NTOK (Bz*Sz)

typedef short bf16x8 __attribute__((ext_vector_type(8)));
typedef float f32x4 __attribute__((ext_vector_type(4)));

// ---------- helpers ----------
__device__ __forceinline__ unsigned short f2bf(float f) {
  unsigned u = __float_as_uint(f);
  unsigned r = (u + 0x7fffu + ((u >> 16) & 1u)) >> 16;
  return (unsigned short)r;
}

__device__ __forceinline__ float fast_tanh(float x) {
  float e = __expf(2.0f * x);
  return 1.0f - 2.0f / (e + 1.0f);
}

// direct global->LDS 16B async copy (CK idiom)
__device__ __forceinline__ void gload16(const void* gp, void* lp) {
  __builtin_amdgcn_global_load_lds(
      (const __attribute__((address_space(1))) unsigned int*)(unsigned long long)(uintptr_t)gp,
      (__attribute__((address_space(3))) unsigned int*)(unsigned int)(uintptr_t)lp,
      16, 0, 0);
}

// ---------- K0: segment ids / sep positions ----------
__global__ __launch_bounds__(256) void k_seg(
    const int* __restrict__ ids, const int* __restrict__ sep_p,
    int* __restrict__ segid, int* __restrict__ seppos,
    int* __restrict__ nsent, int* __restrict__ neff)
{
  int b = blockIdx.x, tid = threadIdx.x;
  int sep = *sep_p;
  __shared__ int cnt[256];
  __shared__ int total_s;
  const int* row = &ids[b*Sz];
  int base = tid*8;
  int loc[8];
  int c = 0;
  #pragma unroll
  for (int i = 0; i < 8; i++) { loc[i] = row[base+i]; c += (loc[i]==sep) ? 1 : 0; }
  cnt[tid] = c;
  __syncthreads();
  if (tid == 0) {
    int run = 0;
    for (int t = 0; t < 256; t++) { int tmp = cnt[t]; cnt[t] = run; run += tmp; }
    total_s = run;
    nsent[b] = run;
    neff[b]  = run > 0 ? run : 1;
  }
  __syncthreads();
  int total = total_s;
  int seg = cnt[tid];
  #pragma unroll
  for (int i = 0; i < 8; i++) {
    int s = base + i;
    bool issep = (loc[i]==sep);
    if (issep && seg < MSz) seppos[b*MSz + seg] = s;
    bool valid = (s >= 1) && !issep && (seg < total);
    segid[b*Sz + s] = valid ? seg : -1;
    if (issep) seg++;
  }
}

// ---------- convert fp32 -> bf16 (vectorized, 4/thread) ----------
__global__ __launch_bounds__(256) void k_cvt_bf16(
    const float* __restrict__ src, unsigned short* __restrict__ dst, int n4)
{
  int i = blockIdx.x*256 + threadIdx.x;
  if (i >= n4) return;
  float4 v = ((const float4*)src)[i];
  ushort4 o;
  o.x = f2bf(v.x); o.y = f2bf(v.y); o.z = f2bf(v.z); o.w = f2bf(v.w);
  ((ushort4*)dst)[i] = o;
}

// ---------- transpose + convert: dst[c][r] = bf16(src[r][c]) ----------
__global__ __launch_bounds__(256) void k_tr_cvt(
    const float* __restrict__ src, unsigned short* __restrict__ dst,
    int rows, int cols)
{
  __shared__ float t[32][33];
  int c0 = blockIdx.x*32, r0 = blockIdx.y*32;
  int cx = threadIdx.x & 31, ry = threadIdx.x >> 5;
  #pragma unroll
  for (int p = 0; p < 4; p++)
    t[ry + p*8][cx] = src[(size_t)(r0 + ry + p*8)*cols + c0 + cx];
  __syncthreads();
  #pragma unroll
  for (int p = 0; p < 4; p++) {
    int i = ry + p*8;
    dst[(size_t)(c0 + i)*rows + r0 + cx] = f2bf(t[cx][i]);
  }
}

// ---------- K1: scores = tanh(h1@Wp+bp)@vp via bf16 MFMA ----------
// block: 128 tokens, loop j over 6 chunks of 128; 4 waves x (2 row-tiles x 8 col-tiles)
__global__ __launch_bounds__(256) void k_scores_mfma(
    const unsigned short* __restrict__ h1b, const unsigned short* __restrict__ wpT,
    const float* __restrict__ bp, const float* __restrict__ vp,
    float* __restrict__ scores)
{
  __shared__ unsigned short As[4096];  // 512 cells x 8 bf16, cell = kgrp*128 + m
  __shared__ unsigned short Bs[4096];
  __shared__ float bps[Hz];
  __shared__ float vps[Hz];
  const int tid = threadIdx.x;
  const int wave = tid >> 6, lane = tid & 63;
  const int ml = lane & 15, kg = lane >> 4;
  const size_t tok0 = (size_t)blockIdx.x * 128;
  for (int i = tid; i < Hz; i += 256) { bps[i] = bp[i]; vps[i] = vp[i]; }
  float part[2][4] = {{0,0,0,0},{0,0,0,0}};
  for (int j0 = 0; j0 < Hz; j0 += 128) {
    f32x4 acc[2][8];
    #pragma unroll
    for (int rt = 0; rt < 2; rt++)
      #pragma unroll
      for (int ct = 0; ct < 8; ct++) acc[rt][ct] = (f32x4){0.f,0.f,0.f,0.f};
    for (int k0 = 0; k0 < Hz; k0 += 32) {
      __syncthreads();
      #pragma unroll
      for (int l = 0; l < 2; l++) {
        int slot = l*256 + tid;
        int m = slot & 127, kgs = slot >> 7;
        gload16(&h1b[(tok0 + m)*Hz + k0 + kgs*8], &As[slot*8]);
        gload16(&wpT[(size_t)(j0 + m)*Hz + k0 + kgs*8], &Bs[slot*8]);
      }
      __syncthreads();
      bf16x8 af0 = *(const bf16x8*)&As[(kg*128 + wave*32 + ml)*8];
      bf16x8 af1 = *(const bf16x8*)&As[(kg*128 + wave*32 + 16 + ml)*8];
      #pragma unroll
      for (int ct = 0; ct < 8; ct++) {
        bf16x8 bfr = *(const bf16x8*)&Bs[(kg*128 + ct*16 + ml)*8];
        acc[0][ct] = __builtin_amdgcn_mfma_f32_16x16x32_bf16(af0, bfr, acc[0][ct], 0, 0, 0);
        acc[1][ct] = __builtin_amdgcn_mfma_f32_16x16x32_bf16(af1, bfr, acc[1][ct], 0, 0, 0);
      }
    }
    // epilogue: tanh(c + bp)*vp, accumulate per row
    #pragma unroll
    for (int ct = 0; ct < 8; ct++) {
      int col = j0 + ct*16 + ml;
      float bpv = bps[col], vpv = vps[col];
      #pragma unroll
      for (int rt = 0; rt < 2; rt++)
        #pragma unroll
        for (int i = 0; i < 4; i++)
          part[rt][i] += fast_tanh(acc[rt][ct][i] + bpv) * vpv;
    }
  }
  // reduce across the 16 col-lanes (bits 0..3 of lane)
  #pragma unroll
  for (int rt = 0; rt < 2; rt++)
    #pragma unroll
    for (int i = 0; i < 4; i++) {
      float v = part[rt][i];
      v += __shfl_xor(v, 1); v += __shfl_xor(v, 2);
      v += __shfl_xor(v, 4); v += __shfl_xor(v, 8);
      if (ml == 0) scores[tok0 + wave*32 + rt*16 + kg*4 + i] = v;
    }
}

// ---------- K2: per-(b,seg) softmax ----------
__device__ inline unsigned fenc(float f){ unsigned u = __float_as_uint(f); return (u & 0x80000000u) ? ~u : (u | 0x80000000u); }
__device__ inline float fdec(unsigned u){ return (u & 0x80000000u) ? __uint_as_float(u & 0x7fffffffu) : __uint_as_float(~u); }

__global__ __launch_bounds__(256) void k_softmax_seg(
    const float* __restrict__ scores, const int* __restrict__ segid,
    float* __restrict__ w)
{
  int b = blockIdx.x, tid = threadIdx.x;
  __shared__ unsigned menc[MSz];
  __shared__ float msh[MSz];
  __shared__ float zsh[MSz];
  if (tid < MSz) { menc[tid] = 0u; zsh[tid] = 0.f; }
  __syncthreads();
  for (int s = tid; s < Sz; s += 256) {
    int g = segid[b*Sz + s];
    if (g >= 0 && g < MSz) atomicMax(&menc[g], fenc(scores[b*Sz+s]));
  }
  __syncthreads();
  if (tid < MSz) msh[tid] = fdec(menc[tid]);
  __syncthreads();
  for (int s = tid; s < Sz; s += 256) {
    int g = segid[b*Sz + s];
    float e = 0.f;
    if (g >= 0 && g < MSz) { e = expf(scores[b*Sz+s] - msh[g]); atomicAdd(&zsh[g], e); }
    w[b*Sz + s] = e;
  }
  __syncthreads();
  if (tid < MSz) zsh[tid] = (zsh[tid] > 0.f) ? 1.0f/zsh[tid] : 1.0f;
  __syncthreads();
  for (int s = tid; s < Sz; s += 256) {
    int g = segid[b*Sz + s];
    if (g >= 0 && g < MSz) w[b*Sz + s] *= zsh[g];
  }
}

// ---------- K3: weighted sentence sums -> x rows ----------
__global__ __launch_bounds__(256) void k_sent(
    const float* __restrict__ h1, const float* __restrict__ w,
    const int* __restrict__ seppos, const int* __restrict__ nsent,
    const int* __restrict__ neff, float* __restrict__ x)
{
  int s = blockIdx.x, b = blockIdx.y, tid = threadIdx.x;
  int ne = neff[b], ns = nsent[b];
  if (s >= ne) return;
  float* xr = &x[((size_t)b*Lz + s)*Hz];
  if (ns == 0) {
    const float* hr = &h1[(size_t)b*Sz*Hz];
    xr[tid] = hr[tid]; xr[tid+256] = hr[tid+256]; xr[tid+512] = hr[tid+512];
    return;
  }
  int start = (s == 0) ? 1 : seppos[b*MSz + s - 1] + 1;
  int end = seppos[b*MSz + s];
  float a0=0.f, a1=0.f, a2=0.f;
  for (int t = start; t < end; t++) {
    float wv = w[b*Sz + t];
    const float* hr = &h1[((size_t)b*Sz + t)*Hz];
    a0 += wv*hr[tid]; a1 += wv*hr[tid+256]; a2 += wv*hr[tid+512];
  }
  xr[tid]=a0; xr[tid+256]=a1; xr[tid+512]=a2;
}

// ---------- K4: place fact_cls rows ----------
__global__ __launch_bounds__(256) void k_facts(
    const float* __restrict__ fc, const int* __restrict__ fcnt,
    const int* __restrict__ neff, float* __restrict__ x)
{
  int f = blockIdx.x, b = blockIdx.y, tid = threadIdx.x;
  if (f >= fcnt[b]) return;
  int pos = neff[b] + f;
  if (pos >= Lz) return;
  float* xr = &x[((size_t)b*Lz + pos)*Hz];
  const float* fr = &fc[((size_t)b*FMAXz + f)*Hz];
  xr[tid] = fr[tid]; xr[tid+256] = fr[tid+256]; xr[tid+512] = fr[tid+512];
}

// ---------- pack bias [bk|bv] ----------
__global__ __launch_bounds__(256) void k_packb(
    const float* __restrict__ bk, const float* __restrict__ bv, float* __restrict__ bcat)
{
  int i = blockIdx.x*256 + threadIdx.x;
  if (i < Hz) bcat[i] = bk[i];
  else if (i < 2*Hz) bcat[i] = bv[i - Hz];
}

// ---------- K5: kv = xb @ [Wk|Wv] + bias via bf16 MFMA ----------
__global__ __launch_bounds__(256) void k_kv_mfma(
    const unsigned short* __restrict__ xb, const unsigned short* __restrict__ wkvT,
    const float* __restrict__ bcat, float* __restrict__ kv)
{
  __shared__ unsigned short As[4096];
  __shared__ unsigned short Bs[4096];
  const int tid = threadIdx.x;
  const int wave = tid >> 6, lane = tid & 63;
  const int ml = lane & 15, kg = lane >> 4;
  const int j0 = blockIdx.x * 128;
  const size_t m0 = (size_t)blockIdx.y * 128;
  f32x4 acc[2][8];
  #pragma unroll
  for (int rt = 0; rt < 2; rt++)
    #pragma unroll
    for (int ct = 0; ct < 8; ct++) acc[rt][ct] = (f32x4){0.f,0.f,0.f,0.f};
  for (int k0 = 0; k0 < Hz; k0 += 32) {
    __syncthreads();
    #pragma unroll
    for (int l = 0; l < 2; l++) {
      int slot = l*256 + tid;
      int m = slot & 127, kgs = slot >> 7;
      gload16(&xb[(m0 + m)*Hz + k0 + kgs*8], &As[slot*8]);
      gload16(&wkvT[(size_t)(j0 + m)*Hz + k0 + kgs*8], &Bs[slot*8]);
    }
    __syncthreads();
    bf16x8 af0 = *(const bf16x8*)&As[(kg*128 + wave*32 + ml)*8];
    bf16x8 af1 = *(const bf16x8*)&As[(kg*128 + wave*32 + 16 + ml)*8];
    #pragma unroll
    for (int ct = 0; ct < 8; ct++) {
      bf16x8 bfr = *(const bf16x8*)&Bs[(kg*128 + ct*16 + ml)*8];
      acc[0][ct] = __builtin_amdgcn_mfma_f32_16x16x32_bf16(af0, bfr, acc[0][ct], 0, 0, 0);
      acc[1][ct] = __builtin_amdgcn_mfma_f32_16x16x32_bf16(af1, bfr, acc[1][ct], 0, 0, 0);
    }
  }
  #pragma unroll
  for (int ct = 0; ct < 8; ct++) {
    int col = j0 + ct*16 + ml;
    float bb = bcat[col];
    #pragma unroll
    for (int rt = 0; rt < 2; rt++)
      #pragma unroll
      for (int i = 0; i < 4; i++) {
        size_t row = m0 + wave*32 + rt*16 + kg*4 + i;
        kv[row*1536 + col] = acc[rt][ct][i] + bb;
      }
  }
}

// ---------- K6: small-M GEMV: C[32,N] = act(A[32,K]@W[K,N] + bias (+resid)) ----------
// 16 cols/block, 16-way K-split within block
__global__ __launch_bounds__(256) void k_gemv32(
    const float* __restrict__ A, int astr,
    const float* __restrict__ W,
    const float* __restrict__ bias,
    const float* __restrict__ resid, int rstride,
    float* __restrict__ C, int K, int N, int act)
{
  __shared__ float As2[32*128];
  __shared__ float red[4][16][32];
  const int tid = threadIdx.x;
  const int c = tid & 15, ks = tid >> 4;
  const int j = blockIdx.x*16 + c;
  float acc[32];
  #pragma unroll
  for (int b = 0; b < 32; b++) acc[b] = 0.f;
  for (int k0 = 0; k0 < K; k0 += 128) {
    __syncthreads();
    #pragma unroll
    for (int p = 0; p < 4; p++) {
      int e = (p*256 + tid)*4;
      int b = e >> 7, kk = e & 127;
      *(float4*)&As2[b*128+kk] = *(const float4*)&A[(size_t)b*astr + k0 + kk];
    }
    __syncthreads();
    #pragma unroll
    for (int q = 0; q < 8; q++) {
      int kk = ks*8 + q;
      float wv = W[(size_t)(k0+kk)*N + j];
      #pragma unroll
      for (int b = 0; b < 32; b++) acc[b] += As2[b*128+kk]*wv;
    }
  }
  // reduce the 4 k-slices within each wave (lane bits 4,5)
  #pragma unroll
  for (int b = 0; b < 32; b++) {
    float v = acc[b];
    v += __shfl_xor(v, 16);
    v += __shfl_xor(v, 32);
    acc[b] = v;
  }
  int wave = tid >> 6, lane = tid & 63;
  if (lane < 16) {
    #pragma unroll
    for (int b = 0; b < 32; b++) red[wave][c][b] = acc[b];
  }
  __syncthreads();
  int c2 = tid & 15, b0 = tid >> 4;
  int j2 = blockIdx.x*16 + c2;
  #pragma unroll
  for (int h = 0; h < 2; h++) {
    int b = b0 + h*16;
    float v = red[0][c2][b] + red[1][c2][b] + red[2][c2][b] + red[3][c2][b];
    v += bias[j2];
    if (resid) v += resid[(size_t)b*rstride + j2];
    if (act == 1) v = 0.5f*v*(1.0f + erff(v*0.70710678118654752f));
    C[(size_t)b*N + j2] = v;
  }
}

// ---------- K7: attention for query row 0 ----------
__global__ __launch_bounds__(128) void k_attn(
    const float* __restrict__ q0, const float* __restrict__ kv,
    const int* __restrict__ neff, const int* __restrict__ fcnt,
    float* __restrict__ ctx0)
{
  int h = blockIdx.x, b = blockIdx.y, tid = threadIdx.x;
  __shared__ float att[Lz];
  __shared__ float qsh[DHz];
  __shared__ float inv_s;
  if (tid < DHz) qsh[tid] = q0[b*Hz + h*DHz + tid];
  __syncthreads();
  int lv = neff[b] + fcnt[b];
  if (tid < Lz) {
    const float* kr = &kv[((size_t)b*Lz + tid)*1536 + h*DHz];
    float s = 0.f;
    #pragma unroll
    for (int d = 0; d < DHz; d++) s += qsh[d]*kr[d];
    s *= 0.125f;
    if (tid >= lv) s -= 1e9f;
    att[tid] = s;
  }
  __syncthreads();
  if (tid == 0) {
    float m = att[0];
    for (int i = 1; i < Lz; i++) m = fmaxf(m, att[i]);
    float z = 0.f;
    for (int i = 0; i < Lz; i++) { float e = expf(att[i] - m); att[i] = e; z += e; }
    inv_s = 1.f/z;
  }
  __syncthreads();
  float inv = inv_s;
  if (tid < DHz) {
    float cvv = 0.f;
    for (int m2 = 0; m2 < Lz; m2++)
      cvv += att[m2] * kv[((size_t)b*Lz + m2)*1536 + Hz + h*DHz + tid];
    ctx0[b*Hz + h*DHz + tid] = cvv*inv;
  }
}

// ---------- block sum helper ----------
__device__ inline float block_sum_256(float v, float* red)
{
  int tid = threadIdx.x;
  red[tid] = v; __syncthreads();
  for (int off = 128; off > 0; off >>= 1) {
    if (tid < off) red[tid] += red[tid + off];
    __syncthreads();
  }
  float r = red[0];
  __syncthreads();
  return r;
}

// ---------- K8: LayerNorm over 32 rows of 768 ----------
__global__ __launch_bounds__(256) void k_ln32(
    const float* __restrict__ in, const float* __restrict__ g,
    const float* __restrict__ bt, float* __restrict__ out)
{
  int b = blockIdx.x, tid = threadIdx.x;
  __shared__ float red[256];
  float a0 = in[b*Hz+tid], a1 = in[b*Hz+tid+256], a2 = in[b*Hz+tid+512];
  float mu = block_sum_256(a0+a1+a2, red) * (1.0f/Hz);
  float d0=a0-mu, d1=a1-mu, d2=a2-mu;
  float var = block_sum_256(d0*d0+d1*d1+d2*d2, red) * (1.0f/Hz);
  float rs = rsqrtf(var + 1e-12f);
  out[b*Hz+tid]     = d0*rs*g[tid]     + bt[tid];
  out[b*Hz+tid+256] = d1*rs*g[tid+256] + bt[tid+256];
  out[b*Hz+tid+512] = d2*rs*g[tid+512] + bt[tid+512];
}

extern "C" void kernel_launch(void* const* d_in, const int* in_sizes, int n_in,
                              void* d_out, int out_size, void* d_ws, size_t ws_size,
                              hipStream_t stream)
{
  (void)in_sizes; (void)n_in; (void)out_size; (void)ws_size;
  const float* hidden1  = (const float*)d_in[0];
  const float* fact_cls = (const float*)d_in[1];
  const float* Wp   = (const float*)d_in[2];
  const float* bp   = (const float*)d_in[3];
  const float* vp   = (const float*)d_in[4];
  const float* Wq   = (const float*)d_in[5];
  const float* bq   = (const float*)d_in[6];
  const float* Wk   = (const float*)d_in[7];
  const float* bk   = (const float*)d_in[8];
  const float* Wv   = (const float*)d_in[9];
  const float* bv   = (const float*)d_in[10];
  const float* Wo   = (const float*)d_in[11];
  const float* bo   = (const float*)d_in[12];
  const float* ln1g = (const float*)d_in[13];
  const float* ln1b = (const float*)d_in[14];
  const float* Wf1  = (const float*)d_in[15];
  const float* bf1  = (const float*)d_in[16];
  const float* Wf2  = (const float*)d_in[17];
  const float* bf2  = (const float*)d_in[18];
  const float* ln2g = (const float*)d_in[19];
  const float* ln2b = (const float*)d_in[20];
  const int* input_ids   = (const int*)d_in[21];
  const int* facts_count = (const int*)d_in[22];
  const int* sep_id      = (const int*)d_in[24];

  char* ws = (char*)d_ws;
  size_t off = 0;
  auto alloc = [&](size_t bytes) -> void* {
    void* p = ws + off; off += (bytes + 255) & ~(size_t)255; return p;
  };
  unsigned short* h1b  = (unsigned short*)alloc(sizeof(short)*(size_t)NTOK*Hz);
  unsigned short* wpT  = (unsigned short*)alloc(sizeof(short)*(size_t)Hz*Hz);
  unsigned short* wkvT = (unsigned short*)alloc(sizeof(short)*(size_t)Hz*1536);
  unsigned short* xb   = (unsigned short*)alloc(sizeof(short)*(size_t)Bz*Lz*Hz);
  float* x      = (float*)alloc(sizeof(float)*(size_t)Bz*Lz*Hz);
  float* kv     = (float*)alloc(sizeof(float)*(size_t)Bz*Lz*1536);
  float* bcat   = (float*)alloc(sizeof(float)*1536);
  float* scores = (float*)alloc(sizeof(float)*NTOK);
  float* w      = (float*)alloc(sizeof(float)*NTOK);
  int*   segid  = (int*)alloc(sizeof(int)*NTOK);
  int*   seppos = (int*)alloc(sizeof(int)*Bz*MSz);
  int*   nsent  = (int*)alloc(sizeof(int)*Bz);
  int*   neff   = (int*)alloc(sizeof(int)*Bz);
  float* q0     = (float*)alloc(sizeof(float)*Bz*Hz);
  float* ctx0   = (float*)alloc(sizeof(float)*Bz*Hz);
  float* tmp0   = (float*)alloc(sizeof(float)*Bz*Hz);
  float* y0     = (float*)alloc(sizeof(float)*Bz*Hz);
  float* tmp1   = (float*)alloc(sizeof(float)*Bz*Hz);
  float* ffnmid = (float*)alloc(sizeof(float)*Bz*FFNz);

  // conversions / preprocessing
  k_cvt_bf16<<<(NTOK*Hz/4 + 255)/256, 256, 0, stream>>>(hidden1, h1b, NTOK*Hz/4);
  k_tr_cvt<<<dim3(Hz/32, Hz/32), 256, 0, stream>>>(Wp, wpT, Hz, Hz);
  k_seg<<<Bz, 256, 0, stream>>>(input_ids, sep_id, segid, seppos, nsent, neff);

  // scores path
  k_scores_mfma<<<NTOK/128, 256, 0, stream>>>(h1b, wpT, bp, vp, scores);
  k_softmax_seg<<<Bz, 256, 0, stream>>>(scores, segid, w);

  // build x
  hipMemsetAsync(x, 0, sizeof(float)*(size_t)Bz*Lz*Hz, stream);
  k_sent<<<dim3(MSz, Bz), 256, 0, stream>>>(hidden1, w, seppos, nsent, neff, x);
  k_facts<<<dim3(FMAXz, Bz), 256, 0, stream>>>(fact_cls, facts_count, neff, x);
  k_cvt_bf16<<<(Bz*Lz*Hz/4 + 255)/256, 256, 0, stream>>>(x, xb, Bz*Lz*Hz/4);

  // KV projection
  k_tr_cvt<<<dim3(Hz/32, Hz/32), 256, 0, stream>>>(Wk, wkvT, Hz, Hz);
  k_tr_cvt<<<dim3(Hz/32, Hz/32), 256, 0, stream>>>(Wv, wkvT + (size_t)Hz*Hz, Hz, Hz);
  k_packb<<<6, 256, 0, stream>>>(bk, bv, bcat);
  k_kv_mfma<<<dim3(12, Bz*Lz/128), 256, 0, stream>>>(xb, wkvT, bcat, kv);

  // attention (row 0 query only)
  k_gemv32<<<Hz/16, 256, 0, stream>>>(x, Lz*Hz, Wq, bq, nullptr, 0, q0, Hz, Hz, 0);
  k_attn<<<dim3(NHz, Bz), 128, 0, stream>>>(q0, kv, neff, facts_count, ctx0);
  k_gemv32<<<Hz/16, 256, 0, stream>>>(ctx0, Hz, Wo, bo, x, Lz*Hz, tmp0, Hz, Hz, 0);
  k_ln32<<<Bz, 256, 0, stream>>>(tmp0, ln1g, ln1b, y0);

  // FFN (row 0 only)
  k_gemv32<<<FFNz/16, 256, 0, stream>>>(y0, Hz, Wf1, bf1, nullptr, 0, ffnmid, Hz, FFNz, 1);
  k_gemv32<<<Hz/16, 256, 0, stream>>>(ffnmid, FFNz, Wf2, bf2, y0, Hz, tmp1, FFNz, Hz, 0);
  k_ln32<<<Bz, 256, 0, stream>>>(tmp1, ln2g, ln2b, (float*)d_out);
}

// Round 3
// 718.322 us; speedup vs baseline: 2.8353x; 1.0041x over previous
//
#include <hip/hip_runtime.h>
#include <math.h>

#define Bz   32
#define Sz   2048
#define Hz   768
#define FMAXz 32
#define MSz  64
#define NHz  12
#define DHz  64
#define Lz   96
#define FFNz 3072
#define NTOK (Bz*Sz)

typedef short bf16x8 __attribute__((ext_vector_type(8)));
typedef float f32x4 __attribute__((ext_vector_type(4)));

// ---------- helpers ----------
__device__ __forceinline__ unsigned short f2bf(float f) {
  unsigned u = __float_as_uint(f);
  unsigned r = (u + 0x7fffu + ((u >> 16) & 1u)) >> 16;
  return (unsigned short)r;
}

__device__ __forceinline__ float fast_tanh(float x) {
  float e = __expf(2.0f * x);
  return 1.0f - 2.0f / (e + 1.0f);
}

__device__ __forceinline__ void gload16(const void* gp, void* lp) {
  __builtin_amdgcn_global_load_lds(
      (const __attribute__((address_space(1))) unsigned int*)(unsigned long long)(uintptr_t)gp,
      (__attribute__((address_space(3))) unsigned int*)(unsigned int)(uintptr_t)lp,
      16, 0, 0);
}

// ---------- K0: segment ids / sep positions ----------
__global__ __launch_bounds__(256) void k_seg(
    const int* __restrict__ ids, const int* __restrict__ sep_p,
    int* __restrict__ segid, int* __restrict__ seppos,
    int* __restrict__ nsent, int* __restrict__ neff)
{
  int b = blockIdx.x, tid = threadIdx.x;
  int sep = *sep_p;
  __shared__ int cnt[256];
  __shared__ int total_s;
  const int* row = &ids[b*Sz];
  int base = tid*8;
  int loc[8];
  int c = 0;
  #pragma unroll
  for (int i = 0; i < 8; i++) { loc[i] = row[base+i]; c += (loc[i]==sep) ? 1 : 0; }
  cnt[tid] = c;
  __syncthreads();
  if (tid == 0) {
    int run = 0;
    for (int t = 0; t < 256; t++) { int tmp = cnt[t]; cnt[t] = run; run += tmp; }
    total_s = run;
    nsent[b] = run;
    neff[b]  = run > 0 ? run : 1;
  }
  __syncthreads();
  int total = total_s;
  int seg = cnt[tid];
  #pragma unroll
  for (int i = 0; i < 8; i++) {
    int s = base + i;
    bool issep = (loc[i]==sep);
    if (issep && seg < MSz) seppos[b*MSz + seg] = s;
    bool valid = (s >= 1) && !issep && (seg < total);
    segid[b*Sz + s] = valid ? seg : -1;
    if (issep) seg++;
  }
}

// ---------- convert fp32 -> bf16 ----------
__global__ __launch_bounds__(256) void k_cvt_bf16(
    const float* __restrict__ src, unsigned short* __restrict__ dst, int n4)
{
  int i = blockIdx.x*256 + threadIdx.x;
  if (i >= n4) return;
  float4 v = ((const float4*)src)[i];
  ushort4 o;
  o.x = f2bf(v.x); o.y = f2bf(v.y); o.z = f2bf(v.z); o.w = f2bf(v.w);
  ((ushort4*)dst)[i] = o;
}

// ---------- transpose + convert ----------
__global__ __launch_bounds__(256) void k_tr_cvt(
    const float* __restrict__ src, unsigned short* __restrict__ dst,
    int rows, int cols)
{
  __shared__ float t[32][33];
  int c0 = blockIdx.x*32, r0 = blockIdx.y*32;
  int cx = threadIdx.x & 31, ry = threadIdx.x >> 5;
  #pragma unroll
  for (int p = 0; p < 4; p++)
    t[ry + p*8][cx] = src[(size_t)(r0 + ry + p*8)*cols + c0 + cx];
  __syncthreads();
  #pragma unroll
  for (int p = 0; p < 4; p++) {
    int i = ry + p*8;
    dst[(size_t)(c0 + i)*rows + r0 + cx] = f2bf(t[cx][i]);
  }
}

// ---------- K1: scores partial: block = (j-chunk, token-tile), atomicAdd ----------
__global__ __launch_bounds__(256) void k_scores_mfma(
    const unsigned short* __restrict__ h1b, const unsigned short* __restrict__ wpT,
    const float* __restrict__ bp, const float* __restrict__ vp,
    float* __restrict__ scores)
{
  __shared__ unsigned short As[4096];
  __shared__ unsigned short Bs[4096];
  __shared__ float bps[128], vps[128];
  const int tid = threadIdx.x;
  const int wave = tid >> 6, lane = tid & 63;
  const int ml = lane & 15, kg = lane >> 4;
  const int j0 = blockIdx.x * 128;              // 6 j-chunks, fastest-varying
  const size_t tok0 = (size_t)blockIdx.y * 128; // 512 token tiles
  if (tid < 128) { bps[tid] = bp[j0+tid]; vps[tid] = vp[j0+tid]; }
  f32x4 acc[2][8];
  #pragma unroll
  for (int rt = 0; rt < 2; rt++)
    #pragma unroll
    for (int ct = 0; ct < 8; ct++) acc[rt][ct] = (f32x4){0.f,0.f,0.f,0.f};
  for (int k0 = 0; k0 < Hz; k0 += 32) {
    __syncthreads();
    #pragma unroll
    for (int l = 0; l < 2; l++) {
      int slot = l*256 + tid;
      int m = slot & 127, kgs = slot >> 7;
      gload16(&h1b[(tok0 + m)*Hz + k0 + kgs*8], &As[slot*8]);
      gload16(&wpT[(size_t)(j0 + m)*Hz + k0 + kgs*8], &Bs[slot*8]);
    }
    __syncthreads();
    bf16x8 af0 = *(const bf16x8*)&As[(kg*128 + wave*32 + ml)*8];
    bf16x8 af1 = *(const bf16x8*)&As[(kg*128 + wave*32 + 16 + ml)*8];
    #pragma unroll
    for (int ct = 0; ct < 8; ct++) {
      bf16x8 bfr = *(const bf16x8*)&Bs[(kg*128 + ct*16 + ml)*8];
      acc[0][ct] = __builtin_amdgcn_mfma_f32_16x16x32_bf16(af0, bfr, acc[0][ct], 0, 0, 0);
      acc[1][ct] = __builtin_amdgcn_mfma_f32_16x16x32_bf16(af1, bfr, acc[1][ct], 0, 0, 0);
    }
  }
  float part[2][4] = {{0,0,0,0},{0,0,0,0}};
  #pragma unroll
  for (int ct = 0; ct < 8; ct++) {
    int cl = ct*16 + ml;
    float bpv = bps[cl], vpv = vps[cl];
    #pragma unroll
    for (int rt = 0; rt < 2; rt++)
      #pragma unroll
      for (int i = 0; i < 4; i++)
        part[rt][i] += fast_tanh(acc[rt][ct][i] + bpv) * vpv;
  }
  #pragma unroll
  for (int rt = 0; rt < 2; rt++)
    #pragma unroll
    for (int i = 0; i < 4; i++) {
      float v = part[rt][i];
      v += __shfl_xor(v, 1); v += __shfl_xor(v, 2);
      v += __shfl_xor(v, 4); v += __shfl_xor(v, 8);
      if (ml == 0) atomicAdd(&scores[tok0 + wave*32 + rt*16 + kg*4 + i], v);
    }
}

// ---------- K2: per-(b,seg) softmax ----------
__device__ inline unsigned fenc(float f){ unsigned u = __float_as_uint(f); return (u & 0x80000000u) ? ~u : (u | 0x80000000u); }
__device__ inline float fdec(unsigned u){ return (u & 0x80000000u) ? __uint_as_float(u & 0x7fffffffu) : __uint_as_float(~u); }

__global__ __launch_bounds__(256) void k_softmax_seg(
    const float* __restrict__ scores, const int* __restrict__ segid,
    float* __restrict__ w)
{
  int b = blockIdx.x, tid = threadIdx.x;
  __shared__ unsigned menc[MSz];
  __shared__ float msh[MSz];
  __shared__ float zsh[MSz];
  if (tid < MSz) { menc[tid] = 0u; zsh[tid] = 0.f; }
  __syncthreads();
  for (int s = tid; s < Sz; s += 256) {
    int g = segid[b*Sz + s];
    if (g >= 0 && g < MSz) atomicMax(&menc[g], fenc(scores[b*Sz+s]));
  }
  __syncthreads();
  if (tid < MSz) msh[tid] = fdec(menc[tid]);
  __syncthreads();
  for (int s = tid; s < Sz; s += 256) {
    int g = segid[b*Sz + s];
    float e = 0.f;
    if (g >= 0 && g < MSz) { e = expf(scores[b*Sz+s] - msh[g]); atomicAdd(&zsh[g], e); }
    w[b*Sz + s] = e;
  }
  __syncthreads();
  if (tid < MSz) zsh[tid] = (zsh[tid] > 0.f) ? 1.0f/zsh[tid] : 1.0f;
  __syncthreads();
  for (int s = tid; s < Sz; s += 256) {
    int g = segid[b*Sz + s];
    if (g >= 0 && g < MSz) w[b*Sz + s] *= zsh[g];
  }
}

// ---------- K3: weighted sentence sums -> x rows ----------
__global__ __launch_bounds__(256) void k_sent(
    const float* __restrict__ h1, const float* __restrict__ w,
    const int* __restrict__ seppos, const int* __restrict__ nsent,
    const int* __restrict__ neff, float* __restrict__ x)
{
  int s = blockIdx.x, b = blockIdx.y, tid = threadIdx.x;
  int ne = neff[b], ns = nsent[b];
  if (s >= ne) return;
  float* xr = &x[((size_t)b*Lz + s)*Hz];
  if (ns == 0) {
    const float* hr = &h1[(size_t)b*Sz*Hz];
    xr[tid] = hr[tid]; xr[tid+256] = hr[tid+256]; xr[tid+512] = hr[tid+512];
    return;
  }
  int start = (s == 0) ? 1 : seppos[b*MSz + s - 1] + 1;
  int end = seppos[b*MSz + s];
  float a0=0.f, a1=0.f, a2=0.f;
  for (int t = start; t < end; t++) {
    float wv = w[b*Sz + t];
    const float* hr = &h1[((size_t)b*Sz + t)*Hz];
    a0 += wv*hr[tid]; a1 += wv*hr[tid+256]; a2 += wv*hr[tid+512];
  }
  xr[tid]=a0; xr[tid+256]=a1; xr[tid+512]=a2;
}

// ---------- K4: place fact_cls rows ----------
__global__ __launch_bounds__(256) void k_facts(
    const float* __restrict__ fc, const int* __restrict__ fcnt,
    const int* __restrict__ neff, float* __restrict__ x)
{
  int f = blockIdx.x, b = blockIdx.y, tid = threadIdx.x;
  if (f >= fcnt[b]) return;
  int pos = neff[b] + f;
  if (pos >= Lz) return;
  float* xr = &x[((size_t)b*Lz + pos)*Hz];
  const float* fr = &fc[((size_t)b*FMAXz + f)*Hz];
  xr[tid] = fr[tid]; xr[tid+256] = fr[tid+256]; xr[tid+512] = fr[tid+512];
}

// ---------- pack bias [bk|bv] ----------
__global__ __launch_bounds__(256) void k_packb(
    const float* __restrict__ bk, const float* __restrict__ bv, float* __restrict__ bcat)
{
  int i = blockIdx.x*256 + threadIdx.x;
  if (i < Hz) bcat[i] = bk[i];
  else if (i < 2*Hz) bcat[i] = bv[i - Hz];
}

// ---------- K5: kv = xb @ [Wk|Wv] + bias via bf16 MFMA ----------
__global__ __launch_bounds__(256) void k_kv_mfma(
    const unsigned short* __restrict__ xb, const unsigned short* __restrict__ wkvT,
    const float* __restrict__ bcat, float* __restrict__ kv)
{
  __shared__ unsigned short As[4096];
  __shared__ unsigned short Bs[4096];
  const int tid = threadIdx.x;
  const int wave = tid >> 6, lane = tid & 63;
  const int ml = lane & 15, kg = lane >> 4;
  const int j0 = blockIdx.x * 128;
  const size_t m0 = (size_t)blockIdx.y * 128;
  f32x4 acc[2][8];
  #pragma unroll
  for (int rt = 0; rt < 2; rt++)
    #pragma unroll
    for (int ct = 0; ct < 8; ct++) acc[rt][ct] = (f32x4){0.f,0.f,0.f,0.f};
  for (int k0 = 0; k0 < Hz; k0 += 32) {
    __syncthreads();
    #pragma unroll
    for (int l = 0; l < 2; l++) {
      int slot = l*256 + tid;
      int m = slot & 127, kgs = slot >> 7;
      gload16(&xb[(m0 + m)*Hz + k0 + kgs*8], &As[slot*8]);
      gload16(&wkvT[(size_t)(j0 + m)*Hz + k0 + kgs*8], &Bs[slot*8]);
    }
    __syncthreads();
    bf16x8 af0 = *(const bf16x8*)&As[(kg*128 + wave*32 + ml)*8];
    bf16x8 af1 = *(const bf16x8*)&As[(kg*128 + wave*32 + 16 + ml)*8];
    #pragma unroll
    for (int ct = 0; ct < 8; ct++) {
      bf16x8 bfr = *(const bf16x8*)&Bs[(kg*128 + ct*16 + ml)*8];
      acc[0][ct] = __builtin_amdgcn_mfma_f32_16x16x32_bf16(af0, bfr, acc[0][ct], 0, 0, 0);
      acc[1][ct] = __builtin_amdgcn_mfma_f32_16x16x32_bf16(af1, bfr, acc[1][ct], 0, 0, 0);
    }
  }
  #pragma unroll
  for (int ct = 0; ct < 8; ct++) {
    int col = j0 + ct*16 + ml;
    float bb = bcat[col];
    #pragma unroll
    for (int rt = 0; rt < 2; rt++)
      #pragma unroll
      for (int i = 0; i < 4; i++) {
        size_t row = m0 + wave*32 + rt*16 + kg*4 + i;
        kv[row*1536 + col] = acc[rt][ct][i] + bb;
      }
  }
}

// ---------- K6: split-K GEMV partials ----------
// part[by][32][N](cols bx*64..) = A_eff[32, by*192..+192] @ W[., N]
// A_eff: plain rows (aparts==0) or gelu(sum_p partials + abias) (aparts>0, agelu)
__global__ __launch_bounds__(256) void k_gemv_part(
    const float* __restrict__ A, int astr, int aparts, const float* __restrict__ abias,
    int agelu, const float* __restrict__ W, float* __restrict__ part, int N)
{
  __shared__ float As2[32*196];      // 196 pad: 16B-aligned rows, bank spread
  __shared__ float red[4][32][64];
  const int tid = threadIdx.x;
  const int k0 = blockIdx.y * 192;
  // stage A (with optional partial-fold + bias + gelu)
  {
    int b = tid >> 3, t8 = tid & 7;
    #pragma unroll
    for (int i = 0; i < 24; i++) {
      int kk = t8*24 + i;
      float v;
      if (aparts == 0) {
        v = A[(size_t)b*astr + k0 + kk];
      } else {
        v = abias[k0 + kk];
        for (int p = 0; p < aparts; p++) v += A[((size_t)p*32 + b)*astr + k0 + kk];
        if (agelu) v = 0.5f*v*(1.0f + erff(v*0.70710678118654752f));
      }
      As2[b*196 + kk] = v;
    }
  }
  __syncthreads();
  const int jc = tid & 63, w = tid >> 6;
  const int j = blockIdx.x*64 + jc;
  float acc[32];
  #pragma unroll
  for (int b = 0; b < 32; b++) acc[b] = 0.f;
  for (int kq = 0; kq < 12; kq++) {
    int kk = w*48 + kq*4;
    float w0 = W[(size_t)(k0+kk  )*N + j];
    float w1 = W[(size_t)(k0+kk+1)*N + j];
    float w2 = W[(size_t)(k0+kk+2)*N + j];
    float w3 = W[(size_t)(k0+kk+3)*N + j];
    #pragma unroll
    for (int b = 0; b < 32; b++) {
      float4 a = *(const float4*)&As2[b*196 + kk];
      acc[b] += a.x*w0 + a.y*w1 + a.z*w2 + a.w*w3;
    }
  }
  #pragma unroll
  for (int b = 0; b < 32; b++) red[w][b][jc] = acc[b];
  __syncthreads();
  #pragma unroll
  for (int r = 0; r < 8; r++) {
    int o = r*256 + tid;          // 2048 outputs
    int b = o >> 6, jc2 = o & 63;
    float s = red[0][b][jc2] + red[1][b][jc2] + red[2][b][jc2] + red[3][b][jc2];
    part[((size_t)blockIdx.y*32 + b)*N + blockIdx.x*64 + jc2] = s;
  }
}

// ---------- K7: attention for query row 0 (folds q partials + bq) ----------
__global__ __launch_bounds__(128) void k_attn(
    const float* __restrict__ qpart, const float* __restrict__ bq,
    const float* __restrict__ kv,
    const int* __restrict__ neff, const int* __restrict__ fcnt,
    float* __restrict__ ctx0)
{
  int h = blockIdx.x, b = blockIdx.y, tid = threadIdx.x;
  __shared__ float att[Lz];
  __shared__ float qsh[DHz];
  __shared__ float inv_s;
  if (tid < DHz) {
    int col = h*DHz + tid;
    float qv = bq[col];
    #pragma unroll
    for (int p = 0; p < 4; p++) qv += qpart[((size_t)p*32 + b)*Hz + col];
    qsh[tid] = qv;
  }
  __syncthreads();
  int lv = neff[b] + fcnt[b];
  if (tid < Lz) {
    const float* kr = &kv[((size_t)b*Lz + tid)*1536 + h*DHz];
    float s = 0.f;
    #pragma unroll
    for (int d = 0; d < DHz; d++) s += qsh[d]*kr[d];
    s *= 0.125f;
    if (tid >= lv) s -= 1e9f;
    att[tid] = s;
  }
  __syncthreads();
  if (tid == 0) {
    float m = att[0];
    for (int i = 1; i < Lz; i++) m = fmaxf(m, att[i]);
    float z = 0.f;
    for (int i = 0; i < Lz; i++) { float e = expf(att[i] - m); att[i] = e; z += e; }
    inv_s = 1.f/z;
  }
  __syncthreads();
  float inv = inv_s;
  if (tid < DHz) {
    float cvv = 0.f;
    for (int m2 = 0; m2 < Lz; m2++)
      cvv += att[m2] * kv[((size_t)b*Lz + m2)*1536 + Hz + h*DHz + tid];
    ctx0[b*Hz + h*DHz + tid] = cvv*inv;
  }
}

// ---------- block sum helper ----------
__device__ inline float block_sum_256(float v, float* red)
{
  int tid = threadIdx.x;
  red[tid] = v; __syncthreads();
  for (int off = 128; off > 0; off >>= 1) {
    if (tid < off) red[tid] += red[tid + off];
    __syncthreads();
  }
  float r = red[0];
  __syncthreads();
  return r;
}

// ---------- K8: fold P partials + bias + resid, then LayerNorm ----------
__global__ __launch_bounds__(256) void k_ln32_fold(
    const float* __restrict__ part, int P,
    const float* __restrict__ bias,
    const float* __restrict__ resid, int rstr,
    const float* __restrict__ g, const float* __restrict__ bt,
    float* __restrict__ out)
{
  int b = blockIdx.x, tid = threadIdx.x;
  __shared__ float red[256];
  float a0 = bias[tid]     + resid[(size_t)b*rstr + tid];
  float a1 = bias[tid+256] + resid[(size_t)b*rstr + tid+256];
  float a2 = bias[tid+512] + resid[(size_t)b*rstr + tid+512];
  for (int p = 0; p < P; p++) {
    const float* pr = &part[((size_t)p*32 + b)*Hz];
    a0 += pr[tid]; a1 += pr[tid+256]; a2 += pr[tid+512];
  }
  float mu = block_sum_256(a0+a1+a2, red) * (1.0f/Hz);
  float d0=a0-mu, d1=a1-mu, d2=a2-mu;
  float var = block_sum_256(d0*d0+d1*d1+d2*d2, red) * (1.0f/Hz);
  float rs = rsqrtf(var + 1e-12f);
  out[b*Hz+tid]     = d0*rs*g[tid]     + bt[tid];
  out[b*Hz+tid+256] = d1*rs*g[tid+256] + bt[tid+256];
  out[b*Hz+tid+512] = d2*rs*g[tid+512] + bt[tid+512];
}

extern "C" void kernel_launch(void* const* d_in, const int* in_sizes, int n_in,
                              void* d_out, int out_size, void* d_ws, size_t ws_size,
                              hipStream_t stream)
{
  (void)in_sizes; (void)n_in; (void)out_size; (void)ws_size;
  const float* hidden1  = (const float*)d_in[0];
  const float* fact_cls = (const float*)d_in[1];
  const float* Wp   = (const float*)d_in[2];
  const float* bp   = (const float*)d_in[3];
  const float* vp   = (const float*)d_in[4];
  const float* Wq   = (const float*)d_in[5];
  const float* bq   = (const float*)d_in[6];
  const float* Wk   = (const float*)d_in[7];
  const float* bk   = (const float*)d_in[8];
  const float* Wv   = (const float*)d_in[9];
  const float* bv   = (const float*)d_in[10];
  const float* Wo   = (const float*)d_in[11];
  const float* bo   = (const float*)d_in[12];
  const float* ln1g = (const float*)d_in[13];
  const float* ln1b = (const float*)d_in[14];
  const float* Wf1  = (const float*)d_in[15];
  const float* bf1  = (const float*)d_in[16];
  const float* Wf2  = (const float*)d_in[17];
  const float* bf2  = (const float*)d_in[18];
  const float* ln2g = (const float*)d_in[19];
  const float* ln2b = (const float*)d_in[20];
  const int* input_ids   = (const int*)d_in[21];
  const int* facts_count = (const int*)d_in[22];
  const int* sep_id      = (const int*)d_in[24];

  char* ws = (char*)d_ws;
  size_t off = 0;
  auto alloc = [&](size_t bytes) -> void* {
    void* p = ws + off; off += (bytes + 255) & ~(size_t)255; return p;
  };
  unsigned short* h1b  = (unsigned short*)alloc(sizeof(short)*(size_t)NTOK*Hz);
  unsigned short* wpT  = (unsigned short*)alloc(sizeof(short)*(size_t)Hz*Hz);
  unsigned short* wkvT = (unsigned short*)alloc(sizeof(short)*(size_t)Hz*1536);
  unsigned short* xb   = (unsigned short*)alloc(sizeof(short)*(size_t)Bz*Lz*Hz);
  float* x      = (float*)alloc(sizeof(float)*(size_t)Bz*Lz*Hz);
  float* kv     = (float*)alloc(sizeof(float)*(size_t)Bz*Lz*1536);
  float* bcat   = (float*)alloc(sizeof(float)*1536);
  float* scores = (float*)alloc(sizeof(float)*NTOK);
  float* w      = (float*)alloc(sizeof(float)*NTOK);
  int*   segid  = (int*)alloc(sizeof(int)*NTOK);
  int*   seppos = (int*)alloc(sizeof(int)*Bz*MSz);
  int*   nsent  = (int*)alloc(sizeof(int)*Bz);
  int*   neff   = (int*)alloc(sizeof(int)*Bz);
  float* qpart  = (float*)alloc(sizeof(float)*4*Bz*Hz);
  float* ctx0   = (float*)alloc(sizeof(float)*Bz*Hz);
  float* wopart = (float*)alloc(sizeof(float)*4*Bz*Hz);
  float* y0     = (float*)alloc(sizeof(float)*Bz*Hz);
  float* fpart  = (float*)alloc(sizeof(float)*4*Bz*FFNz);
  float* f2part = (float*)alloc(sizeof(float)*16*Bz*Hz);

  // preprocessing
  k_cvt_bf16<<<(NTOK*Hz/4 + 255)/256, 256, 0, stream>>>(hidden1, h1b, NTOK*Hz/4);
  k_tr_cvt<<<dim3(Hz/32, Hz/32), 256, 0, stream>>>(Wp, wpT, Hz, Hz);
  k_seg<<<Bz, 256, 0, stream>>>(input_ids, sep_id, segid, seppos, nsent, neff);

  // scores path (split-j, atomic accumulate)
  hipMemsetAsync(scores, 0, sizeof(float)*NTOK, stream);
  k_scores_mfma<<<dim3(6, NTOK/128), 256, 0, stream>>>(h1b, wpT, bp, vp, scores);
  k_softmax_seg<<<Bz, 256, 0, stream>>>(scores, segid, w);

  // build x
  hipMemsetAsync(x, 0, sizeof(float)*(size_t)Bz*Lz*Hz, stream);
  k_sent<<<dim3(MSz, Bz), 256, 0, stream>>>(hidden1, w, seppos, nsent, neff, x);
  k_facts<<<dim3(FMAXz, Bz), 256, 0, stream>>>(fact_cls, facts_count, neff, x);
  k_cvt_bf16<<<(Bz*Lz*Hz/4 + 255)/256, 256, 0, stream>>>(x, xb, Bz*Lz*Hz/4);

  // KV projection
  k_tr_cvt<<<dim3(Hz/32, Hz/32), 256, 0, stream>>>(Wk, wkvT, Hz, Hz);
  k_tr_cvt<<<dim3(Hz/32, Hz/32), 256, 0, stream>>>(Wv, wkvT + (size_t)Hz*Hz, Hz, Hz);
  k_packb<<<6, 256, 0, stream>>>(bk, bv, bcat);
  k_kv_mfma<<<dim3(12, Bz*Lz/128), 256, 0, stream>>>(xb, wkvT, bcat, kv);

  // attention tail (row-0 only), split-K partial GEMVs with folded epilogues
  k_gemv_part<<<dim3(Hz/64, 4), 256, 0, stream>>>(x, Lz*Hz, 0, nullptr, 0, Wq, qpart, Hz);
  k_attn<<<dim3(NHz, Bz), 128, 0, stream>>>(qpart, bq, kv, neff, facts_count, ctx0);
  k_gemv_part<<<dim3(Hz/64, 4), 256, 0, stream>>>(ctx0, Hz, 0, nullptr, 0, Wo, wopart, Hz);
  k_ln32_fold<<<Bz, 256, 0, stream>>>(wopart, 4, bo, x, Lz*Hz, ln1g, ln1b, y0);

  // FFN (row-0 only)
  k_gemv_part<<<dim3(FFNz/64, 4), 256, 0, stream>>>(y0, Hz, 0, nullptr, 0, Wf1, fpart, FFNz);
  k_gemv_part<<<dim3(Hz/64, 16), 256, 0, stream>>>(fpart, FFNz, 4, bf1, 1, Wf2, f2part, Hz);
  k_ln32_fold<<<Bz, 256, 0, stream>>>(f2part, 16, bf2, y0, Hz, ln2g, ln2b, (float*)d_out);
}

// Round 5
// 716.341 us; speedup vs baseline: 2.8432x; 1.0028x over previous
//
#include <hip/hip_runtime.h>
#include <math.h>

#define Bz   32
#define Sz   2048
#define Hz   768
#define FMAXz 32
#define MSz  64
#define NHz  12
#define DHz  64
#define Lz   96
#define FFNz 3072
#define NTOK (Bz*Sz)

typedef short bf16x8 __attribute__((ext_vector_type(8)));
typedef float f32x4 __attribute__((ext_vector_type(4)));

// ---------- helpers ----------
__device__ __forceinline__ unsigned short f2bf(float f) {
  unsigned u = __float_as_uint(f);
  unsigned r = (u + 0x7fffu + ((u >> 16) & 1u)) >> 16;
  return (unsigned short)r;
}
__device__ __forceinline__ float bf2f(unsigned short h) {
  return __uint_as_float(((unsigned)h) << 16);
}
__device__ __forceinline__ float fast_tanh(float x) {
  float e = __expf(2.0f * x);
  return 1.0f - 2.0f / (e + 1.0f);
}
__device__ __forceinline__ void gload16(const void* gp, void* lp) {
  __builtin_amdgcn_global_load_lds(
      (const __attribute__((address_space(1))) unsigned int*)(unsigned long long)(uintptr_t)gp,
      (__attribute__((address_space(3))) unsigned int*)(unsigned int)(uintptr_t)lp,
      16, 0, 0);
}

// ---------- K0: sep positions / counts ----------
__global__ __launch_bounds__(256) void k_seg(
    const int* __restrict__ ids, const int* __restrict__ sep_p,
    int* __restrict__ seppos, int* __restrict__ nsent, int* __restrict__ neff)
{
  int b = blockIdx.x, tid = threadIdx.x;
  int sep = *sep_p;
  __shared__ int cnt[256];
  const int* row = &ids[b*Sz];
  int base = tid*8;
  int loc[8];
  int c = 0;
  #pragma unroll
  for (int i = 0; i < 8; i++) { loc[i] = row[base+i]; c += (loc[i]==sep) ? 1 : 0; }
  cnt[tid] = c;
  __syncthreads();
  if (tid == 0) {
    int run = 0;
    for (int t = 0; t < 256; t++) { int tmp = cnt[t]; cnt[t] = run; run += tmp; }
    nsent[b] = run;
    neff[b]  = run > 0 ? run : 1;
  }
  __syncthreads();
  int seg = cnt[tid];
  #pragma unroll
  for (int i = 0; i < 8; i++) {
    bool issep = (loc[i]==sep);
    if (issep && seg < MSz) seppos[b*MSz + seg] = base + i;
    if (issep) seg++;
  }
}

// ---------- convert fp32 -> bf16 ----------
__global__ __launch_bounds__(256) void k_cvt_bf16(
    const float* __restrict__ src, unsigned short* __restrict__ dst, int n4)
{
  int i = blockIdx.x*256 + threadIdx.x;
  if (i >= n4) return;
  float4 v = ((const float4*)src)[i];
  ushort4 o;
  o.x = f2bf(v.x); o.y = f2bf(v.y); o.z = f2bf(v.z); o.w = f2bf(v.w);
  ((ushort4*)dst)[i] = o;
}

// ---------- fused transpose+convert for Wp, Wk, Wv (2D grid, x-mux) ----------
__global__ __launch_bounds__(256) void k_tr3(
    const float* __restrict__ Wp, const float* __restrict__ Wk,
    const float* __restrict__ Wv, unsigned short* __restrict__ wpT,
    unsigned short* __restrict__ wkvT)
{
  int which = blockIdx.x / (Hz/32);
  int bx = blockIdx.x % (Hz/32);
  const float* src; unsigned short* dst;
  if (which == 0)      { src = Wp; dst = wpT; }
  else if (which == 1) { src = Wk; dst = wkvT; }
  else                 { src = Wv; dst = wkvT + (size_t)Hz*Hz; }
  __shared__ float t[32][33];
  int c0 = bx*32, r0 = blockIdx.y*32;
  int cx = threadIdx.x & 31, ry = threadIdx.x >> 5;
  #pragma unroll
  for (int p = 0; p < 4; p++)
    t[ry + p*8][cx] = src[(size_t)(r0 + ry + p*8)*Hz + c0 + cx];
  __syncthreads();
  #pragma unroll
  for (int p = 0; p < 4; p++) {
    int i = ry + p*8;
    dst[(size_t)(c0 + i)*Hz + r0 + cx] = f2bf(t[cx][i]);
  }
}

// ---------- K1: scores partial, BK=64, block=(j-chunk, token-tile), atomicAdd ----------
__global__ __launch_bounds__(256) void k_scores_mfma(
    const unsigned short* __restrict__ h1b, const unsigned short* __restrict__ wpT,
    const float* __restrict__ bp, const float* __restrict__ vp,
    float* __restrict__ scores)
{
  __shared__ unsigned short As[8192];   // 8 kgrp x 128 m cells, 16B each
  __shared__ unsigned short Bs[8192];
  __shared__ float bps[128], vps[128];
  const int tid = threadIdx.x;
  const int wave = tid >> 6, lane = tid & 63;
  const int ml = lane & 15, kg = lane >> 4;
  const int j0 = blockIdx.x * 128;
  const size_t tok0 = (size_t)blockIdx.y * 128;
  if (tid < 128) { bps[tid] = bp[j0+tid]; vps[tid] = vp[j0+tid]; }
  f32x4 acc[2][8];
  #pragma unroll
  for (int rt = 0; rt < 2; rt++)
    #pragma unroll
    for (int ct = 0; ct < 8; ct++) acc[rt][ct] = (f32x4){0.f,0.f,0.f,0.f};
  for (int k0 = 0; k0 < Hz; k0 += 64) {
    __syncthreads();
    #pragma unroll
    for (int l = 0; l < 4; l++) {
      int slot = l*256 + tid;
      int m = slot & 127, kgs = slot >> 7;
      gload16(&h1b[(tok0 + m)*Hz + k0 + kgs*8], &As[slot*8]);
      gload16(&wpT[(size_t)(j0 + m)*Hz + k0 + kgs*8], &Bs[slot*8]);
    }
    __syncthreads();
    #pragma unroll
    for (int s = 0; s < 2; s++) {
      int kb = s*4 + kg;
      bf16x8 af0 = *(const bf16x8*)&As[(kb*128 + wave*32 + ml)*8];
      bf16x8 af1 = *(const bf16x8*)&As[(kb*128 + wave*32 + 16 + ml)*8];
      #pragma unroll
      for (int ct = 0; ct < 8; ct++) {
        bf16x8 bfr = *(const bf16x8*)&Bs[(kb*128 + ct*16 + ml)*8];
        acc[0][ct] = __builtin_amdgcn_mfma_f32_16x16x32_bf16(af0, bfr, acc[0][ct], 0, 0, 0);
        acc[1][ct] = __builtin_amdgcn_mfma_f32_16x16x32_bf16(af1, bfr, acc[1][ct], 0, 0, 0);
      }
    }
  }
  float part[2][4] = {{0,0,0,0},{0,0,0,0}};
  #pragma unroll
  for (int ct = 0; ct < 8; ct++) {
    int cl = ct*16 + ml;
    float bpv = bps[cl], vpv = vps[cl];
    #pragma unroll
    for (int rt = 0; rt < 2; rt++)
      #pragma unroll
      for (int i = 0; i < 4; i++)
        part[rt][i] += fast_tanh(acc[rt][ct][i] + bpv) * vpv;
  }
  #pragma unroll
  for (int rt = 0; rt < 2; rt++)
    #pragma unroll
    for (int i = 0; i < 4; i++) {
      float v = part[rt][i];
      v += __shfl_xor(v, 1); v += __shfl_xor(v, 2);
      v += __shfl_xor(v, 4); v += __shfl_xor(v, 8);
      if (ml == 0) atomicAdd(&scores[tok0 + wave*32 + rt*16 + kg*4 + i], v);
    }
}

// ---------- K2: segmented softmax, one wave per (contiguous) segment ----------
__global__ __launch_bounds__(256) void k_softmax_seg2(
    const float* __restrict__ scores, const int* __restrict__ seppos,
    const int* __restrict__ nsent, float* __restrict__ w)
{
  int b = blockIdx.x;
  int wv = threadIdx.x >> 6, lane = threadIdx.x & 63;
  int ns = nsent[b]; if (ns > MSz) ns = MSz;
  const float* sc = &scores[b*Sz];
  float* wr = &w[b*Sz];
  for (int s = wv; s < ns; s += 4) {
    int start = (s == 0) ? 1 : seppos[b*MSz + s - 1] + 1;
    int end = seppos[b*MSz + s];
    if (end <= start) continue;
    float m = -1e30f;
    for (int t = start + lane; t < end; t += 64) m = fmaxf(m, sc[t]);
    #pragma unroll
    for (int o = 32; o; o >>= 1) m = fmaxf(m, __shfl_xor(m, o));
    float z = 0.f;
    for (int t = start + lane; t < end; t += 64) z += __expf(sc[t] - m);
    #pragma unroll
    for (int o = 32; o; o >>= 1) z += __shfl_xor(z, o);
    float inv = 1.0f / z;
    for (int t = start + lane; t < end; t += 64) wr[t] = __expf(sc[t] - m) * inv;
  }
}

// ---------- K3: build x rows (sent sums from bf16 h1 + fact placement) + xb ----------
__global__ __launch_bounds__(256) void k_build(
    const unsigned short* __restrict__ h1b, const float* __restrict__ h1,
    const float* __restrict__ fc, const float* __restrict__ w,
    const int* __restrict__ seppos, const int* __restrict__ nsent,
    const int* __restrict__ neff, const int* __restrict__ fcnt,
    float* __restrict__ x, unsigned short* __restrict__ xb)
{
  int s = blockIdx.x, b = blockIdx.y, tid = threadIdx.x;
  int ne = neff[b], ns = nsent[b];
  float a0, a1, a2;
  size_t row;
  if (s < MSz) {
    if (s >= ne) return;
    row = (size_t)b*Lz + s;
    if (ns == 0) {
      const float* hr = &h1[(size_t)b*Sz*Hz];
      a0 = hr[tid]; a1 = hr[tid+256]; a2 = hr[tid+512];
    } else {
      int start = (s == 0) ? 1 : seppos[b*MSz + s - 1] + 1;
      int end = seppos[b*MSz + s];
      a0 = a1 = a2 = 0.f;
      for (int t = start; t < end; t++) {
        float wv = w[b*Sz + t];
        const unsigned short* hr = &h1b[((size_t)b*Sz + t)*Hz];
        a0 += wv*bf2f(hr[tid]); a1 += wv*bf2f(hr[tid+256]); a2 += wv*bf2f(hr[tid+512]);
      }
    }
  } else {
    int f = s - MSz;
    if (f >= fcnt[b]) return;
    int pos = ne + f;
    if (pos >= Lz) return;
    row = (size_t)b*Lz + pos;
    const float* fr = &fc[((size_t)b*FMAXz + f)*Hz];
    a0 = fr[tid]; a1 = fr[tid+256]; a2 = fr[tid+512];
  }
  float* xr = &x[row*Hz];
  unsigned short* xbr = &xb[row*Hz];
  xr[tid] = a0; xr[tid+256] = a1; xr[tid+512] = a2;
  xbr[tid] = f2bf(a0); xbr[tid+256] = f2bf(a1); xbr[tid+512] = f2bf(a2);
}

// ---------- K5: kv = xb @ [Wk|Wv] + bias, 64x128 tiles, BK=64 ----------
__global__ __launch_bounds__(256) void k_kv_mfma(
    const unsigned short* __restrict__ xb, const unsigned short* __restrict__ wkvT,
    const float* __restrict__ bk, const float* __restrict__ bv,
    float* __restrict__ kv)
{
  __shared__ unsigned short As[4096];   // 8 kgrp x 64 m
  __shared__ unsigned short Bs[8192];   // 8 kgrp x 128 j
  const int tid = threadIdx.x;
  const int wave = tid >> 6, lane = tid & 63;
  const int ml = lane & 15, kg = lane >> 4;
  const int j0 = blockIdx.x * 128;
  const size_t m0 = (size_t)blockIdx.y * 64;
  f32x4 acc[8];
  #pragma unroll
  for (int ct = 0; ct < 8; ct++) acc[ct] = (f32x4){0.f,0.f,0.f,0.f};
  for (int k0 = 0; k0 < Hz; k0 += 64) {
    __syncthreads();
    #pragma unroll
    for (int l = 0; l < 2; l++) {
      int slot = l*256 + tid;
      int m = slot & 63, kgs = slot >> 6;
      gload16(&xb[(m0 + m)*Hz + k0 + kgs*8], &As[slot*8]);
    }
    #pragma unroll
    for (int l = 0; l < 4; l++) {
      int slot = l*256 + tid;
      int m = slot & 127, kgs = slot >> 7;
      gload16(&wkvT[(size_t)(j0 + m)*Hz + k0 + kgs*8], &Bs[slot*8]);
    }
    __syncthreads();
    #pragma unroll
    for (int s = 0; s < 2; s++) {
      int kb = s*4 + kg;
      bf16x8 af = *(const bf16x8*)&As[(kb*64 + wave*16 + ml)*8];
      #pragma unroll
      for (int ct = 0; ct < 8; ct++) {
        bf16x8 bfr = *(const bf16x8*)&Bs[(kb*128 + ct*16 + ml)*8];
        acc[ct] = __builtin_amdgcn_mfma_f32_16x16x32_bf16(af, bfr, acc[ct], 0, 0, 0);
      }
    }
  }
  #pragma unroll
  for (int ct = 0; ct < 8; ct++) {
    int col = j0 + ct*16 + ml;
    float bb = (col < Hz) ? bk[col] : bv[col - Hz];
    #pragma unroll
    for (int i = 0; i < 4; i++) {
      size_t row = m0 + wave*16 + kg*4 + i;
      kv[row*1536 + col] = acc[ct][i] + bb;
    }
  }
}

// ---------- K6: split-K GEMV partials ----------
__global__ __launch_bounds__(256) void k_gemv_part(
    const float* __restrict__ A, int astr, int aparts, const float* __restrict__ abias,
    int agelu, const float* __restrict__ W, float* __restrict__ part, int N)
{
  __shared__ float As2[32*196];
  __shared__ float red[4][32][64];
  const int tid = threadIdx.x;
  const int k0 = blockIdx.y * 192;
  {
    int b = tid >> 3, t8 = tid & 7;
    #pragma unroll
    for (int i = 0; i < 24; i++) {
      int kk = t8*24 + i;
      float v;
      if (aparts == 0) {
        v = A[(size_t)b*astr + k0 + kk];
      } else {
        v = abias[k0 + kk];
        for (int p = 0; p < aparts; p++) v += A[((size_t)p*32 + b)*astr + k0 + kk];
        if (agelu) v = 0.5f*v*(1.0f + erff(v*0.70710678118654752f));
      }
      As2[b*196 + kk] = v;
    }
  }
  __syncthreads();
  const int jc = tid & 63, w = tid >> 6;
  const int j = blockIdx.x*64 + jc;
  float acc[32];
  #pragma unroll
  for (int b = 0; b < 32; b++) acc[b] = 0.f;
  for (int kq = 0; kq < 12; kq++) {
    int kk = w*48 + kq*4;
    float w0 = W[(size_t)(k0+kk  )*N + j];
    float w1 = W[(size_t)(k0+kk+1)*N + j];
    float w2 = W[(size_t)(k0+kk+2)*N + j];
    float w3 = W[(size_t)(k0+kk+3)*N + j];
    #pragma unroll
    for (int b = 0; b < 32; b++) {
      float4 a = *(const float4*)&As2[b*196 + kk];
      acc[b] += a.x*w0 + a.y*w1 + a.z*w2 + a.w*w3;
    }
  }
  #pragma unroll
  for (int b = 0; b < 32; b++) red[w][b][jc] = acc[b];
  __syncthreads();
  #pragma unroll
  for (int r = 0; r < 8; r++) {
    int o = r*256 + tid;
    int b = o >> 6, jc2 = o & 63;
    float s = red[0][b][jc2] + red[1][b][jc2] + red[2][b][jc2] + red[3][b][jc2];
    part[((size_t)blockIdx.y*32 + b)*N + blockIdx.x*64 + jc2] = s;
  }
}

// ---------- K7: attention for query row 0 (folds q partials + bq) ----------
__global__ __launch_bounds__(128) void k_attn(
    const float* __restrict__ qpart, const float* __restrict__ bq,
    const float* __restrict__ kv,
    const int* __restrict__ neff, const int* __restrict__ fcnt,
    float* __restrict__ ctx0)
{
  int h = blockIdx.x, b = blockIdx.y, tid = threadIdx.x;
  __shared__ float att[Lz];
  __shared__ float qsh[DHz];
  __shared__ float inv_s;
  if (tid < DHz) {
    int col = h*DHz + tid;
    float qv = bq[col];
    #pragma unroll
    for (int p = 0; p < 4; p++) qv += qpart[((size_t)p*32 + b)*Hz + col];
    qsh[tid] = qv;
  }
  __syncthreads();
  int lv = neff[b] + fcnt[b];
  if (tid < Lz) {
    const float* kr = &kv[((size_t)b*Lz + tid)*1536 + h*DHz];
    float s = 0.f;
    #pragma unroll
    for (int d = 0; d < DHz; d++) s += qsh[d]*kr[d];
    s *= 0.125f;
    if (tid >= lv) s -= 1e9f;
    att[tid] = s;
  }
  __syncthreads();
  if (tid == 0) {
    float m = att[0];
    for (int i = 1; i < Lz; i++) m = fmaxf(m, att[i]);
    float z = 0.f;
    for (int i = 0; i < Lz; i++) { float e = __expf(att[i] - m); att[i] = e; z += e; }
    inv_s = 1.f/z;
  }
  __syncthreads();
  float inv = inv_s;
  if (tid < DHz) {
    float cvv = 0.f;
    for (int m2 = 0; m2 < Lz; m2++)
      cvv += att[m2] * kv[((size_t)b*Lz + m2)*1536 + Hz + h*DHz + tid];
    ctx0[b*Hz + h*DHz + tid] = cvv*inv;
  }
}

// ---------- block sum helper ----------
__device__ inline float block_sum_256(float v, float* red)
{
  int tid = threadIdx.x;
  red[tid] = v; __syncthreads();
  for (int off = 128; off > 0; off >>= 1) {
    if (tid < off) red[tid] += red[tid + off];
    __syncthreads();
  }
  float r = red[0];
  __syncthreads();
  return r;
}

// ---------- K8: fold P partials + bias + resid, then LayerNorm ----------
__global__ __launch_bounds__(256) void k_ln32_fold(
    const float* __restrict__ part, int P,
    const float* __restrict__ bias,
    const float* __restrict__ resid, int rstr,
    const float* __restrict__ g, const float* __restrict__ bt,
    float* __restrict__ out)
{
  int b = blockIdx.x, tid = threadIdx.x;
  __shared__ float red[256];
  float a0 = bias[tid]     + resid[(size_t)b*rstr + tid];
  float a1 = bias[tid+256] + resid[(size_t)b*rstr + tid+256];
  float a2 = bias[tid+512] + resid[(size_t)b*rstr + tid+512];
  for (int p = 0; p < P; p++) {
    const float* pr = &part[((size_t)p*32 + b)*Hz];
    a0 += pr[tid]; a1 += pr[tid+256]; a2 += pr[tid+512];
  }
  float mu = block_sum_256(a0+a1+a2, red) * (1.0f/Hz);
  float d0=a0-mu, d1=a1-mu, d2=a2-mu;
  float var = block_sum_256(d0*d0+d1*d1+d2*d2, red) * (1.0f/Hz);
  float rs = rsqrtf(var + 1e-12f);
  out[b*Hz+tid]     = d0*rs*g[tid]     + bt[tid];
  out[b*Hz+tid+256] = d1*rs*g[tid+256] + bt[tid+256];
  out[b*Hz+tid+512] = d2*rs*g[tid+512] + bt[tid+512];
}

extern "C" void kernel_launch(void* const* d_in, const int* in_sizes, int n_in,
                              void* d_out, int out_size, void* d_ws, size_t ws_size,
                              hipStream_t stream)
{
  (void)in_sizes; (void)n_in; (void)out_size; (void)ws_size;
  const float* hidden1  = (const float*)d_in[0];
  const float* fact_cls = (const float*)d_in[1];
  const float* Wp   = (const float*)d_in[2];
  const float* bp   = (const float*)d_in[3];
  const float* vp   = (const float*)d_in[4];
  const float* Wq   = (const float*)d_in[5];
  const float* bq   = (const float*)d_in[6];
  const float* Wk   = (const float*)d_in[7];
  const float* bk   = (const float*)d_in[8];
  const float* Wv   = (const float*)d_in[9];
  const float* bv   = (const float*)d_in[10];
  const float* Wo   = (const float*)d_in[11];
  const float* bo   = (const float*)d_in[12];
  const float* ln1g = (const float*)d_in[13];
  const float* ln1b = (const float*)d_in[14];
  const float* Wf1  = (const float*)d_in[15];
  const float* bf1  = (const float*)d_in[16];
  const float* Wf2  = (const float*)d_in[17];
  const float* bf2  = (const float*)d_in[18];
  const float* ln2g = (const float*)d_in[19];
  const float* ln2b = (const float*)d_in[20];
  const int* input_ids   = (const int*)d_in[21];
  const int* facts_count = (const int*)d_in[22];
  const int* sep_id      = (const int*)d_in[24];

  char* ws = (char*)d_ws;
  size_t off = 0;
  auto alloc = [&](size_t bytes) -> void* {
    void* p = ws + off; off += (bytes + 255) & ~(size_t)255; return p;
  };
  // contiguous zero-init region: scores, xb, x (sizes are 256-multiples)
  float* scores        = (float*)alloc(sizeof(float)*NTOK);
  unsigned short* xb   = (unsigned short*)alloc(sizeof(short)*(size_t)Bz*Lz*Hz);
  float* x             = (float*)alloc(sizeof(float)*(size_t)Bz*Lz*Hz);
  size_t zbytes = (char*)(x + (size_t)Bz*Lz*Hz) - (char*)scores;

  unsigned short* h1b  = (unsigned short*)alloc(sizeof(short)*(size_t)NTOK*Hz);
  unsigned short* wpT  = (unsigned short*)alloc(sizeof(short)*(size_t)Hz*Hz);
  unsigned short* wkvT = (unsigned short*)alloc(sizeof(short)*(size_t)Hz*1536);
  float* kv     = (float*)alloc(sizeof(float)*(size_t)Bz*Lz*1536);
  float* w      = (float*)alloc(sizeof(float)*NTOK);
  int*   seppos = (int*)alloc(sizeof(int)*Bz*MSz);
  int*   nsent  = (int*)alloc(sizeof(int)*Bz);
  int*   neff   = (int*)alloc(sizeof(int)*Bz);
  float* qpart  = (float*)alloc(sizeof(float)*4*Bz*Hz);
  float* ctx0   = (float*)alloc(sizeof(float)*Bz*Hz);
  float* wopart = (float*)alloc(sizeof(float)*4*Bz*Hz);
  float* y0     = (float*)alloc(sizeof(float)*Bz*Hz);
  float* fpart  = (float*)alloc(sizeof(float)*4*Bz*FFNz);
  float* f2part = (float*)alloc(sizeof(float)*16*Bz*Hz);

  // preprocessing
  hipMemsetAsync(scores, 0, zbytes, stream);
  k_cvt_bf16<<<(NTOK*Hz/4 + 255)/256, 256, 0, stream>>>(hidden1, h1b, NTOK*Hz/4);
  k_tr3<<<dim3(3*(Hz/32), Hz/32), 256, 0, stream>>>(Wp, Wk, Wv, wpT, wkvT);
  k_seg<<<Bz, 256, 0, stream>>>(input_ids, sep_id, seppos, nsent, neff);

  // scores path
  k_scores_mfma<<<dim3(6, NTOK/128), 256, 0, stream>>>(h1b, wpT, bp, vp, scores);
  k_softmax_seg2<<<Bz, 256, 0, stream>>>(scores, seppos, nsent, w);

  // build x / xb (sent sums + fact placement)
  k_build<<<dim3(MSz + FMAXz, Bz), 256, 0, stream>>>(
      h1b, hidden1, fact_cls, w, seppos, nsent, neff, facts_count, x, xb);

  // KV projection
  k_kv_mfma<<<dim3(12, Bz*Lz/64), 256, 0, stream>>>(xb, wkvT, bk, bv, kv);

  // attention tail (row-0 only)
  k_gemv_part<<<dim3(Hz/64, 4), 256, 0, stream>>>(x, Lz*Hz, 0, nullptr, 0, Wq, qpart, Hz);
  k_attn<<<dim3(NHz, Bz), 128, 0, stream>>>(qpart, bq, kv, neff, facts_count, ctx0);
  k_gemv_part<<<dim3(Hz/64, 4), 256, 0, stream>>>(ctx0, Hz, 0, nullptr, 0, Wo, wopart, Hz);
  k_ln32_fold<<<Bz, 256, 0, stream>>>(wopart, 4, bo, x, Lz*Hz, ln1g, ln1b, y0);

  // FFN (row-0 only)
  k_gemv_part<<<dim3(FFNz/64, 4), 256, 0, stream>>>(y0, Hz, 0, nullptr, 0, Wf1, fpart, FFNz);
  k_gemv_part<<<dim3(Hz/64, 16), 256, 0, stream>>>(fpart, FFNz, 4, bf1, 1, Wf2, f2part, Hz);
  k_ln32_fold<<<Bz, 256, 0, stream>>>(f2part, 16, bf2, y0, Hz, ln2g, ln2b, (float*)d_out);
}